// Round 16
// baseline (956.453 us; speedup 1.0000x reference)
//
#include <hip/hip_runtime.h>

// ---------------- problem constants ----------------
constexpr int B_  = 2;
constexpr int C_  = 256;
constexpr int H_  = 100;
constexpr int W_  = 152;
constexpr int HW_ = H_ * W_;          // 15200
constexpr int K9 = 9;
constexpr int CK = C_ * K9;           // 2304

constexpr int OFF_INIT = B_ * 80 * HW_;              // 2,432,000
constexpr int OFF_REF  = OFF_INIT + B_ * 18 * HW_;   // 2,979,200

typedef __attribute__((ext_vector_type(8))) short short8;
typedef __attribute__((ext_vector_type(4))) float f32x4;

__device__ inline unsigned short f2b(float f) {
    union { float f; unsigned u; } x; x.f = f;
    unsigned r = x.u + 0x7fff + ((x.u >> 16) & 1);   // RNE
    return (unsigned short)(r >> 16);
}
__device__ inline float b2f(unsigned short b) {
    union { unsigned u; float f; } x; x.u = ((unsigned)b) << 16; return x.f;
}

__device__ inline void load_lds16(const void* g, void* l) {
    __builtin_amdgcn_global_load_lds(
        (const __attribute__((address_space(1))) unsigned int*)g,
        (__attribute__((address_space(3))) unsigned int*)l, 16, 0, 0);
}

// T1: bijective XCD-aware block swizzle (m204 formula).
__device__ inline int3 xcd_swizzle() {
    const int gx = gridDim.x, gxy = gridDim.x * gridDim.y;
    const int nwg = gxy * gridDim.z;
    int orig = blockIdx.x + gx * blockIdx.y + gxy * blockIdx.z;
    int q = nwg >> 3, r = nwg & 7;
    int xcd = orig & 7, idx = orig >> 3;
    int lg = (xcd < r ? xcd * (q + 1) : r * (q + 1) + (xcd - r) * q) + idx;
    int bz = lg / gxy;
    int rem = lg - bz * gxy;
    int by = rem / gx;
    int bx = rem - by * gx;
    return make_int3(bx, by, bz);
}

// ---------------- NCHW fp32 -> NHWC bf16 (input transform) ----------------
__global__ __launch_bounds__(256) void to_nhwc_b16_kernel(
    const float* __restrict__ in, unsigned short* __restrict__ outb)
{
    __shared__ float t[64][65];
    const int lane = threadIdx.x & 63, grp = threadIdx.x >> 6;
    const int p0 = blockIdx.x * 64;
    const int c0 = blockIdx.y * 64;
    const int b  = blockIdx.z;
#pragma unroll
    for (int j = 0; j < 16; j++) {
        int c = c0 + j * 4 + grp;
        int p = p0 + lane;
        float v = (p < HW_) ? in[((size_t)(b * C_ + c)) * HW_ + p] : 0.f;
        t[j * 4 + grp][lane] = v;
    }
    __syncthreads();
#pragma unroll
    for (int j = 0; j < 16; j++) {
        int p = p0 + j * 4 + grp;
        int c = c0 + lane;
        if (p < HW_) outb[((size_t)b * HW_ + p) * C_ + c] = f2b(t[lane][j * 4 + grp]);
    }
}

// ------- weight prep (dual): fp32 [co][ci][3][3] -> bf16 [kk][co][ci]; zero stats ----
__global__ void wprep2_kernel(const float* __restrict__ w0, const float* __restrict__ w1,
                              unsigned short* __restrict__ t0, unsigned short* __restrict__ t1,
                              float* __restrict__ stats)
{
    const int co = blockIdx.x, kk = blockIdx.y, tw = blockIdx.z, ci = threadIdx.x;
    const float* w = tw ? w1 : w0;
    unsigned short* t = tw ? t1 : t0;
    t[((size_t)kk * C_ + co) * C_ + ci] = f2b(w[((size_t)co * C_ + ci) * K9 + kk]);
    if (co == 0 && kk == 0 && tw == 0) {
        stats[ci] = 0.f;
        if (ci < 32) stats[256 + ci] = 0.f;   // zbuf
    }
}

// ---------------- MFMA conv3x3 v8: M=128 x N=128, 48KB LDS + T1 (r15 best) ------
__global__ __launch_bounds__(256) void conv3x3_mfma8_kernel(
    const unsigned short* __restrict__ src0, const unsigned short* __restrict__ src1,
    const unsigned short* __restrict__ wtb0, const unsigned short* __restrict__ wtb1,
    const float* __restrict__ bias0, const float* __restrict__ bias1,
    unsigned short* __restrict__ dst0, unsigned short* __restrict__ dst1,
    float* __restrict__ stats, const unsigned short* __restrict__ zbuf, int relu)
{
    __shared__ __align__(16) short a_lds[2][1024 * 8];   // 2 x 16KB
    __shared__ __align__(16) short b_lds[2][512 * 8];    // 2 x 8KB

    const int3 sw = xcd_swizzle();
    const int z = sw.z, b = z & 1, ch = (z >> 1) & 1, tw = z >> 2;
    const unsigned short* act = tw ? src1 : src0;
    const unsigned short* wtb = tw ? wtb1 : wtb0;
    const float* bias = tw ? bias1 : bias0;
    unsigned short* out = tw ? dst1 : dst0;
    float* st = stats ? stats + tw * 128 : nullptr;

    const int tid = threadIdx.x;
    const int lane = tid & 63, wid = tid >> 6;
    const int wr = wid >> 1, wc = wid & 1;       // wr: x-half, wc: co sub-half
    const int l15 = lane & 15, lq = lane >> 4;
    const int x0 = sw.x * 32, y0 = sw.y * 4;

    // ---- A staging sources (4 x 16B units per thread, 1024 units) ----
    const unsigned short* sbaseA[4];
    int sstepA[4];
#pragma unroll
    for (int j = 0; j < 4; j++) {
        int p = j * 256 + tid;                     // physical 16B unit, 0..1023
        int v = p ^ ((p >> 3) & 7);                // logical (involution)
        const unsigned short* src = zbuf;
        int step = 0;
        if (v < 816) {
            int px = v >> 2, q = v & 3;
            int row = px / 34, col = px - row * 34;
            int y = y0 - 1 + row, x = x0 - 1 + col;
            if (y >= 0 && y < H_ && x >= 0 && x < W_) {
                src = act + ((size_t)(b * HW_ + y * W_ + x) * C_ + q * 8);
                step = 1;
            }
        }
        sbaseA[j] = src; sstepA[j] = step;
    }

    // ---- B staging source offsets: physical p -> logical v = p ^ ((p>>3)&3) ----
    int boff[2];
#pragma unroll
    for (int j = 0; j < 2; j++) {
        int p = j * 256 + tid;
        int v = p ^ ((p >> 3) & 3);
        boff[j] = (v >> 2) * 256 + (v & 3) * 8;    // co_local*256 + q*8
    }

    auto STAGE_A = [&](int ci0, int bi) {
#pragma unroll
        for (int j = 0; j < 4; j++)
            load_lds16(sbaseA[j] + sstepA[j] * ci0,
                       &a_lds[bi][(size_t)(j * 256 + tid) * 8]);
    };
    auto STAGE_B = [&](int kk, int ci0, int bi) {
        const unsigned short* wb = wtb + ((size_t)kk * C_ + ch * 128) * C_ + ci0;
#pragma unroll
        for (int j = 0; j < 2; j++)
            load_lds16(wb + boff[j], &b_lds[bi][(size_t)(j * 256 + tid) * 8]);
    };

    f32x4 acc[4][4];
#pragma unroll
    for (int mf = 0; mf < 4; mf++)
#pragma unroll
        for (int nf = 0; nf < 4; nf++) acc[mf][nf] = (f32x4){0.f, 0.f, 0.f, 0.f};

    STAGE_B(0, 0, 0);
    STAGE_A(0, 0);
    asm volatile("s_waitcnt vmcnt(0)" ::: "memory");
    __builtin_amdgcn_s_barrier();

    int bbuf = 0;
    for (int c = 0; c < 8; c++) {
        const int abuf = c & 1;
        const short* ab = a_lds[abuf];
#pragma unroll
        for (int kk = 0; kk < 9; kk++) {
            // ---- issue next-step stages (stay in flight across the barrier) ----
            int issued = 0;
            if (kk < 8)           { STAGE_B(kk + 1, c * 32, bbuf ^ 1); issued += 2; }
            else if (c < 7)       { STAGE_B(0, (c + 1) * 32, bbuf ^ 1); issued += 2; }
            if (kk == 0 && c < 7) { STAGE_A((c + 1) * 32, abuf ^ 1); issued += 4; }
            // T4: retire only PRIOR-step loads; this step's stay outstanding
            if (issued == 6)      asm volatile("s_waitcnt vmcnt(6)" ::: "memory");
            else if (issued == 2) asm volatile("s_waitcnt vmcnt(2)" ::: "memory");
            else                  asm volatile("s_waitcnt vmcnt(0)" ::: "memory");
            __builtin_amdgcn_s_barrier();

            const int ky = kk / 3, kx = kk % 3;
            short8 af[4], bf[4];
#pragma unroll
            for (int mf = 0; mf < 4; mf++) {
                int lv = ((mf + ky) * 34 + wr * 16 + l15 + kx) * 4 + lq;
                int pu = lv ^ ((lv >> 3) & 7);
                af[mf] = *(const short8*)(ab + pu * 8);
            }
            const short* bb = b_lds[bbuf];
#pragma unroll
            for (int nf = 0; nf < 4; nf++) {
                int u  = (wc * 64 + nf * 16 + l15) * 4 + lq;
                int pu = u ^ ((u >> 3) & 3);
                bf[nf] = *(const short8*)(bb + pu * 8);
            }
            __builtin_amdgcn_s_setprio(1);
#pragma unroll
            for (int nf = 0; nf < 4; nf++)
#pragma unroll
                for (int mf = 0; mf < 4; mf++)
                    acc[mf][nf] = __builtin_amdgcn_mfma_f32_16x16x32_bf16(
                        af[mf], bf[nf], acc[mf][nf], 0, 0, 0);
            __builtin_amdgcn_s_setprio(0);
            asm volatile("" ::: "memory");
            __builtin_amdgcn_s_barrier();
            asm volatile("" ::: "memory");
            bbuf ^= 1;
        }
    }

    // ---- epilogue: bias (+relu) store NHWC bf16, fused GN partial stats ----
#pragma unroll
    for (int nf = 0; nf < 4; nf++) {
        int co = ch * 128 + wc * 64 + nf * 16 + l15;
        float bv = bias[co];
        float s = 0.f, ss = 0.f;
#pragma unroll
        for (int mf = 0; mf < 4; mf++) {
            int y = y0 + mf;                        // always < 100 (25 y-tiles)
#pragma unroll
            for (int r = 0; r < 4; r++) {
                int x = x0 + wr * 16 + lq * 4 + r;
                if (x < W_) {
                    float v = acc[mf][nf][r] + bv;
                    s += v; ss += v * v;
                    out[((size_t)(b * HW_ + y * W_ + x)) * C_ + co] =
                        f2b(relu ? fmaxf(v, 0.f) : v);
                }
            }
        }
        if (st) {
            s  += __shfl_xor(s, 1);  ss += __shfl_xor(ss, 1);
            s  += __shfl_xor(s, 2);  ss += __shfl_xor(ss, 2);
            s  += __shfl_xor(s, 4);  ss += __shfl_xor(ss, 4);
            s  += __shfl_xor(s, 16); ss += __shfl_xor(ss, 16);
            s  += __shfl_xor(s, 32); ss += __shfl_xor(ss, 32);
            if ((lane & 55) == 0) {
                int g = co >> 3;
                atomicAdd(&st[(b * 32 + g) * 2],     s);
                atomicAdd(&st[(b * 32 + g) * 2 + 1], ss);
            }
        }
    }
}

// ----- GN apply + ReLU, dual tower, IN PLACE on bf16 NHWC -----
__global__ __launch_bounds__(256) void gn2_apply_kernel(
    unsigned short* __restrict__ buf0, unsigned short* __restrict__ buf1,
    const float* __restrict__ stats,
    const float* __restrict__ g0, const float* __restrict__ be0,
    const float* __restrict__ g1, const float* __restrict__ be1)
{
    const int tw = blockIdx.y;
    unsigned short* buf = tw ? buf1 : buf0;
    const float* gamma = tw ? g1 : g0;
    const float* beta  = tw ? be1 : be0;
    const float* st = stats + tw * 128;

    const int i = blockIdx.x * 256 + threadIdx.x;   // chunk of 8 channels
    const int c8 = i & 31;            // == group id
    const int b = ((i >> 5) >= HW_) ? 1 : 0;
    const float inv_n = 1.f / (8.f * HW_);
    float s1 = st[(b * 32 + c8) * 2];
    float s2 = st[(b * 32 + c8) * 2 + 1];
    float mean = s1 * inv_n;
    float var  = s2 * inv_n - mean * mean;
    float rs = rsqrtf(var + 1e-5f);

    short8 v8 = *(const short8*)(buf + (size_t)i * 8);
    float vo[8];
#pragma unroll
    for (int j = 0; j < 8; j++) {
        int c = c8 * 8 + j;
        float ga = gamma[c] * rs;
        float be = beta[c] - mean * ga;
        vo[j] = fmaxf(fmaf(b2f((unsigned short)v8[j]), ga, be), 0.f);
    }
    unsigned pk[4];
#pragma unroll
    for (int j = 0; j < 4; j++)
        pk[j] = (unsigned)f2b(vo[2 * j]) | ((unsigned)f2b(vo[2 * j + 1]) << 16);
    *(int4*)(buf + (size_t)i * 8) = make_int4(pk[0], pk[1], pk[2], pk[3]);
}

// ---------------- MFMA deformable conv v7: register-hoisted sampling params ------
// Same algorithm as deform3, but each thread's sampling descriptors (corner
// addresses pre-swizzled, weights, s_lds destinations) are hoisted into
// registers before the chunk loop: the per-chunk sampling chain is just
// {4 reads at reg-held addr -> pack -> write}, units independent -> ILP.
__global__ __launch_bounds__(256) void deform7_mfma_kernel(
    const unsigned short* __restrict__ feat0, const unsigned short* __restrict__ feat1,
    const float* __restrict__ pts,
    const unsigned short* __restrict__ wtb0, const unsigned short* __restrict__ wtb1,
    unsigned short* __restrict__ out0, unsigned short* __restrict__ out1,
    const unsigned short* __restrict__ zbuf)
{
    __shared__ __align__(16) short s_lds[32 * 296];   // A-tile [px][kk*32+ci] pad
    __shared__ __align__(16) short f_lds[512 * 8];    // feat window (384 real + pad)
    __shared__ int   p_ref[288][4];
    __shared__ float p_wgt[288][4];

    const int3 sw = xcd_swizzle();
    const int z = sw.z, b = z & 1, tw = z >> 1;
    const unsigned short* feat = tw ? feat1 : feat0;
    const unsigned short* wtb  = tw ? wtb1 : wtb0;
    unsigned short* out        = tw ? out1 : out0;

    const int tid = threadIdx.x;
    const int lane = tid & 63, wc = tid >> 6;
    const int l15 = lane & 15, lq = lane >> 4;
    const int x0 = sw.x * 8, y0 = sw.y * 4;

    // ---- staging sources (2 per thread) for the 8x12 window ----
    const unsigned short* sbase[2];
    int sstep[2];
#pragma unroll
    for (int j = 0; j < 2; j++) {
        int p = (wc + j * 4) * 64 + lane;          // physical unit 0..511
        int v = p ^ ((p >> 3) & 7);                // logical
        const unsigned short* src = zbuf;
        int step = 0;
        if (v < 384) {
            int pix = v >> 2, q = v & 3;
            int wy = pix / 12, wx = pix - wy * 12;
            int y = y0 - 2 + wy, x = x0 - 2 + wx;
            if (y >= 0 && y < H_ && x >= 0 && x < W_) {
                src = feat + ((size_t)(b * HW_ + y * W_ + x) * C_ + q * 8);
                step = 1;
            }
        }
        sbase[j] = src; sstep[j] = step;
    }

    // ---- bilinear setup: 288 (px,tap) pairs into LDS (cross-thread exchange) ----
    for (int pr = tid; pr < 288; pr += 256) {
        int px_l = pr / 9, kk = pr - px_l * 9;
        int y = y0 + (px_l >> 3), x = x0 + (px_l & 7);
        const float* pb = pts + ((size_t)b * 18 + 2 * kk) * HW_ + y * W_ + x;
        float oy = pb[0], ox = pb[HW_];
        float gy = (float)y + oy, gx = (float)x + ox;
        float fy0 = floorf(gy), fx0 = floorf(gx);
        float dy = gy - fy0, dx = gx - fx0;
        int iy0 = (int)fy0, ix0 = (int)fx0;
        float wy2[2] = {1.f - dy, dy}, wx2[2] = {1.f - dx, dx};
#pragma unroll
        for (int cy = 0; cy < 2; cy++)
#pragma unroll
            for (int cx = 0; cx < 2; cx++) {
                int yy = iy0 + cy, xx = ix0 + cx;
                bool valid = (yy >= 0) && (yy < H_) && (xx >= 0) && (xx < W_);
                int ref = 0;
                float w = 0.f;
                if (valid) {
                    w = wy2[cy] * wx2[cx];
                    int wy = yy - (y0 - 2), wx = xx - (x0 - 2);
                    if (wy >= 0 && wy < 8 && wx >= 0 && wx < 12)
                        ref = wy * 12 + wx;                       // in-window
                    else
                        ref = -(int)((b * HW_ + yy * W_ + xx) * C_) - 1;  // global
                }
                p_ref[pr][cy * 2 + cx] = ref;
                p_wgt[pr][cy * 2 + cx] = w;
            }
    }

    __syncthreads();   // params ready

    // ---- hoist this thread's 4-5 unit descriptors into registers ----
    // unit j handles u = j*256 + tid (u<1152); waves 0-1 carry the 5th unit.
    const int nu_extra = (tid < 128) ? 1 : 0;
    int  rr_[5][4];      // >=0: f_lds element offset (pre-swizzled, q folded)
                         // <0 : -(global elem offset + q*8) - 1
    float4 wg_[5];
    int  dso_[5];        // s_lds element destination
#pragma unroll
    for (int j = 0; j < 5; j++) {
        int u = j * 256 + tid;
        if (j == 4 && !nu_extra) u = tid;          // dummy (never used)
        int q = u & 3, pr = u >> 2;
        int px_l = pr / 9, kk = pr - px_l * 9;
        dso_[j] = px_l * 296 + kk * 32 + q * 8;
        wg_[j] = *(const float4*)p_wgt[pr];
        int4 rf = *(const int4*)p_ref[pr];
        int rv[4] = {rf.x, rf.y, rf.z, rf.w};
#pragma unroll
        for (int c2 = 0; c2 < 4; c2++) {
            int r = rv[c2];
            if (r >= 0) {
                int uu = r * 4 + q;
                int pu = uu ^ ((uu >> 3) & 7);
                rr_[j][c2] = pu * 8;
            } else {
                rr_[j][c2] = -((-r - 1) + q * 8) - 1;
            }
        }
    }

    f32x4 acc[2][4];
#pragma unroll
    for (int mf = 0; mf < 2; mf++)
#pragma unroll
        for (int nf = 0; nf < 4; nf++) acc[mf][nf] = (f32x4){0.f, 0.f, 0.f, 0.f};

    auto STAGE = [&](int ci0) {
#pragma unroll
        for (int j = 0; j < 2; j++)
            load_lds16(sbase[j] + sstep[j] * ci0,
                       &f_lds[((wc + j * 4) * 64) * 8]);
    };

    STAGE(0);
    __syncthreads();

    for (int c = 0; c < 8; c++) {
        const int ci0 = c * 32;
        // ---- sample A-tile: 4(+1) independent units, addresses in registers ----
#pragma unroll
        for (int j = 0; j < 5; j++) {
            if (j == 4 && !nu_extra) break;        // wave-uniform skip
            short8 cv[4];
#pragma unroll
            for (int c2 = 0; c2 < 4; c2++) {
                int r = rr_[j][c2];
                cv[c2] = (r >= 0) ? *(const short8*)(f_lds + r)
                                  : *(const short8*)(feat + (-r - 1) + ci0);
            }
            float4 wg = wg_[j];
            unsigned pk[4];
#pragma unroll
            for (int e = 0; e < 4; e++) {
                float r0 = wg.x * b2f((unsigned short)cv[0][2 * e])
                         + wg.y * b2f((unsigned short)cv[1][2 * e])
                         + wg.z * b2f((unsigned short)cv[2][2 * e])
                         + wg.w * b2f((unsigned short)cv[3][2 * e]);
                float r1 = wg.x * b2f((unsigned short)cv[0][2 * e + 1])
                         + wg.y * b2f((unsigned short)cv[1][2 * e + 1])
                         + wg.z * b2f((unsigned short)cv[2][2 * e + 1])
                         + wg.w * b2f((unsigned short)cv[3][2 * e + 1]);
                asm("v_cvt_pk_bf16_f32 %0, %1, %2" : "=v"(pk[e]) : "v"(r0), "v"(r1));
            }
            *(int4*)(s_lds + dso_[j]) = make_int4(pk[0], pk[1], pk[2], pk[3]);
        }
        __syncthreads();            // A complete; feat window consumed
        if (c < 7) STAGE(ci0 + 32); // restage window (latency hidden by MFMA)

        // ---- MFMA over 9 taps ----
#pragma unroll
        for (int kk = 0; kk < 9; kk++) {
            short8 af[2];
#pragma unroll
            for (int mf = 0; mf < 2; mf++)
                af[mf] = *(const short8*)(s_lds + (mf * 16 + l15) * 296 + kk * 32 + lq * 8);
#pragma unroll
            for (int nf = 0; nf < 4; nf++) {
                int co = wc * 64 + nf * 16 + l15;
                short8 bf = *(const short8*)(wtb + ((size_t)(kk * C_ + co)) * C_ + ci0 + lq * 8);
#pragma unroll
                for (int mf = 0; mf < 2; mf++)
                    acc[mf][nf] = __builtin_amdgcn_mfma_f32_16x16x32_bf16(
                        af[mf], bf, acc[mf][nf], 0, 0, 0);
            }
        }
        __syncthreads();            // stage drained (vmcnt0); A free
    }

    // ---- epilogue: relu -> bf16 NHWC ----
#pragma unroll
    for (int nf = 0; nf < 4; nf++) {
        int co = wc * 64 + nf * 16 + l15;
#pragma unroll
        for (int mf = 0; mf < 2; mf++) {
#pragma unroll
            for (int r = 0; r < 4; r++) {
                int px_l = mf * 16 + lq * 4 + r;
                int y = y0 + (px_l >> 3), x = x0 + (px_l & 7);
                out[((size_t)(b * HW_ + y * W_ + x)) * C_ + co] =
                    f2b(fmaxf(acc[mf][nf][r], 0.f));
            }
        }
    }
}

// ---------------- 1x1 conv from NHWC bf16 feat, out NCHW fp32 ----------------
template <int NOg>
__global__ __launch_bounds__(256) void conv1x1_kernel(
    const unsigned short* __restrict__ feat, const float* __restrict__ w,
    const float* __restrict__ bias, const float* __restrict__ addsrc,
    float* __restrict__ outp, int O)
{
    const int lane = threadIdx.x & 63, og = threadIdx.x >> 6;
    const int px = blockIdx.x * 64 + lane;
    const int b = (px >= HW_) ? 1 : 0;
    const int rem = px - b * HW_;
    const short8* f8 = (const short8*)(feat + (size_t)px * C_);

    float acc[NOg];
#pragma unroll
    for (int j = 0; j < NOg; j++) acc[j] = 0.f;

    for (int c8 = 0; c8 < 32; c8++) {
        short8 v8 = f8[c8];
        float vf[8];
#pragma unroll
        for (int e = 0; e < 8; e++) vf[e] = b2f((unsigned short)v8[e]);
#pragma unroll
        for (int j = 0; j < NOg; j++) {
            int o = og * NOg + j;
            if (o < O) {
                const float* wr = w + (size_t)o * C_ + c8 * 8;
                float4 w0 = *(const float4*)wr;
                float4 w1 = *(const float4*)(wr + 4);
                acc[j] = fmaf(vf[0], w0.x, acc[j]);
                acc[j] = fmaf(vf[1], w0.y, acc[j]);
                acc[j] = fmaf(vf[2], w0.z, acc[j]);
                acc[j] = fmaf(vf[3], w0.w, acc[j]);
                acc[j] = fmaf(vf[4], w1.x, acc[j]);
                acc[j] = fmaf(vf[5], w1.y, acc[j]);
                acc[j] = fmaf(vf[6], w1.z, acc[j]);
                acc[j] = fmaf(vf[7], w1.w, acc[j]);
            }
        }
    }
#pragma unroll
    for (int j = 0; j < NOg; j++) {
        int o = og * NOg + j;
        if (o < O) {
            float val = acc[j] + bias[o];
            size_t oi = ((size_t)(b * O + o)) * HW_ + rem;
            if (addsrc) val += addsrc[oi];
            outp[oi] = val;
        }
    }
}

// ---------------- host launch ----------------
extern "C" void kernel_launch(void* const* d_in, const int* in_sizes, int n_in,
                              void* d_out, int out_size, void* d_ws, size_t ws_size,
                              hipStream_t stream)
{
    (void)in_sizes; (void)n_in; (void)out_size; (void)ws_size;

    const float* x           = (const float*)d_in[0];
    const float* cls_w       = (const float*)d_in[1];
    const float* cls_b       = (const float*)d_in[2];
    const float* cls_gn_g    = (const float*)d_in[3];
    const float* cls_gn_b    = (const float*)d_in[4];
    const float* reg_w       = (const float*)d_in[5];
    const float* reg_b       = (const float*)d_in[6];
    const float* reg_gn_g    = (const float*)d_in[7];
    const float* reg_gn_b    = (const float*)d_in[8];
    const float* init_conv_w = (const float*)d_in[9];
    const float* init_conv_b = (const float*)d_in[10];
    const float* init_out_w  = (const float*)d_in[11];
    const float* init_out_b  = (const float*)d_in[12];
    const float* cls_dcn_w   = (const float*)d_in[13];
    const float* cls_out_w   = (const float*)d_in[14];
    const float* cls_out_b   = (const float*)d_in[15];
    const float* ref_dcn_w   = (const float*)d_in[16];
    const float* ref_out_w   = (const float*)d_in[17];
    const float* ref_out_b   = (const float*)d_in[18];

    float* out = (float*)d_out;

    const size_t NF = (size_t)B_ * C_ * HW_;   // 7,782,400 elements
    unsigned short* xb16 = (unsigned short*)d_ws;
    unsigned short* bA   = xb16 + NF;
    unsigned short* bB   = bA + NF;
    unsigned short* bC   = bB + NF;
    unsigned short* bD   = bC + NF;
    unsigned short* wtb0 = bD + NF;                    // 589,824 bf16
    unsigned short* wtb1 = wtb0 + (size_t)CK * C_;
    float* stats = (float*)(wtb1 + (size_t)CK * C_);   // 256 stats + 32 zbuf
    const unsigned short* zbuf = (const unsigned short*)(stats + 256);

    const dim3 convGrid2(5, 25, 8);       // dual tower, M=128 x N=128
    const dim3 convGrid1(5, 25, 4);       // single tower (tw=0)
    const dim3 wprepGrid2(C_, 9, 2);
    const dim3 wprepGrid1(C_, 9, 1);
    const dim3 nhwcGrid((HW_ + 63) / 64, C_ / 64, B_);
    const dim3 gnGrid((B_ * HW_ * 32) / 256, 2);
    const dim3 deformGrid1(W_ / 8, H_ / 4, 2);       // (19, 25, 2) single tower
    const int  px_blocks = (B_ * HW_) / 64;          // 475

    to_nhwc_b16_kernel<<<nhwcGrid, 256, 0, stream>>>(x, xb16);

    // --- stage 0: xb16 -> bA (cls), bC (pts) ---
    wprep2_kernel<<<wprepGrid2, 256, 0, stream>>>(cls_w, reg_w, wtb0, wtb1, stats);
    conv3x3_mfma8_kernel<<<convGrid2, 256, 0, stream>>>(
        xb16, xb16, wtb0, wtb1, cls_b, reg_b, bA, bC, stats, zbuf, 0);
    gn2_apply_kernel<<<gnGrid, 256, 0, stream>>>(
        bA, bC, stats, cls_gn_g, cls_gn_b, reg_gn_g, reg_gn_b);

    // --- stage 1: bA -> bB, bC -> bD ---
    wprep2_kernel<<<wprepGrid2, 256, 0, stream>>>(
        cls_w + (size_t)C_ * CK, reg_w + (size_t)C_ * CK, wtb0, wtb1, stats);
    conv3x3_mfma8_kernel<<<convGrid2, 256, 0, stream>>>(
        bA, bC, wtb0, wtb1, cls_b + C_, reg_b + C_, bB, bD, stats, zbuf, 0);
    gn2_apply_kernel<<<gnGrid, 256, 0, stream>>>(
        bB, bD, stats, cls_gn_g + C_, cls_gn_b + C_, reg_gn_g + C_, reg_gn_b + C_);

    // --- stage 2: bB -> bA (clsF), bD -> bC (ptsF) ---
    wprep2_kernel<<<wprepGrid2, 256, 0, stream>>>(
        cls_w + 2 * (size_t)C_ * CK, reg_w + 2 * (size_t)C_ * CK, wtb0, wtb1, stats);
    conv3x3_mfma8_kernel<<<convGrid2, 256, 0, stream>>>(
        bB, bD, wtb0, wtb1, cls_b + 2 * C_, reg_b + 2 * C_, bA, bC, stats, zbuf, 0);
    gn2_apply_kernel<<<gnGrid, 256, 0, stream>>>(
        bA, bC, stats, cls_gn_g + 2 * C_, cls_gn_b + 2 * C_,
        reg_gn_g + 2 * C_, reg_gn_b + 2 * C_);

    // --- init branch: relu(conv3x3(ptsF=bC)) -> bD -> 1x1 -> pts_out_init ---
    wprep2_kernel<<<wprepGrid1, 256, 0, stream>>>(init_conv_w, nullptr, wtb0, nullptr, stats);
    conv3x3_mfma8_kernel<<<convGrid1, 256, 0, stream>>>(
        bC, nullptr, wtb0, nullptr, init_conv_b, nullptr, bD, nullptr, nullptr, zbuf, 1);
    conv1x1_kernel<5><<<px_blocks, 256, 0, stream>>>(
        bD, init_out_w, init_out_b, nullptr, out + OFF_INIT, 18);

    // --- deforms (split dispatches) ---
    wprep2_kernel<<<wprepGrid2, 256, 0, stream>>>(cls_dcn_w, ref_dcn_w, wtb0, wtb1, stats);
    deform7_mfma_kernel<<<deformGrid1, 256, 0, stream>>>(
        bA, nullptr, out + OFF_INIT, wtb0, nullptr, bB, nullptr, zbuf);
    deform7_mfma_kernel<<<deformGrid1, 256, 0, stream>>>(
        bC, nullptr, out + OFF_INIT, wtb1, nullptr, bD, nullptr, zbuf);

    // --- tails ---
    conv1x1_kernel<20><<<px_blocks, 256, 0, stream>>>(
        bB, cls_out_w, cls_out_b, nullptr, out, 80);
    conv1x1_kernel<5><<<px_blocks, 256, 0, stream>>>(
        bD, ref_out_w, ref_out_b, out + OFF_INIT, out + OFF_REF, 18);
}

// Round 17
// 920.012 us; speedup vs baseline: 1.0396x; 1.0396x over previous
//
#include <hip/hip_runtime.h>

// ---------------- problem constants ----------------
constexpr int B_  = 2;
constexpr int C_  = 256;
constexpr int H_  = 100;
constexpr int W_  = 152;
constexpr int HW_ = H_ * W_;          // 15200
constexpr int K9 = 9;
constexpr int CK = C_ * K9;           // 2304

constexpr int OFF_INIT = B_ * 80 * HW_;              // 2,432,000
constexpr int OFF_REF  = OFF_INIT + B_ * 18 * HW_;   // 2,979,200

typedef __attribute__((ext_vector_type(8))) short short8;
typedef __attribute__((ext_vector_type(4))) float f32x4;

__device__ inline unsigned short f2b(float f) {
    union { float f; unsigned u; } x; x.f = f;
    unsigned r = x.u + 0x7fff + ((x.u >> 16) & 1);   // RNE
    return (unsigned short)(r >> 16);
}
__device__ inline float b2f(unsigned short b) {
    union { unsigned u; float f; } x; x.u = ((unsigned)b) << 16; return x.f;
}

__device__ inline void load_lds16(const void* g, void* l) {
    __builtin_amdgcn_global_load_lds(
        (const __attribute__((address_space(1))) unsigned int*)g,
        (__attribute__((address_space(3))) unsigned int*)l, 16, 0, 0);
}

// T1: bijective XCD-aware block swizzle (m204 formula).
__device__ inline int3 xcd_swizzle() {
    const int gx = gridDim.x, gxy = gridDim.x * gridDim.y;
    const int nwg = gxy * gridDim.z;
    int orig = blockIdx.x + gx * blockIdx.y + gxy * blockIdx.z;
    int q = nwg >> 3, r = nwg & 7;
    int xcd = orig & 7, idx = orig >> 3;
    int lg = (xcd < r ? xcd * (q + 1) : r * (q + 1) + (xcd - r) * q) + idx;
    int bz = lg / gxy;
    int rem = lg - bz * gxy;
    int by = rem / gx;
    int bx = rem - by * gx;
    return make_int3(bx, by, bz);
}

// ---------------- NCHW fp32 -> NHWC bf16 (input transform) ----------------
__global__ __launch_bounds__(256) void to_nhwc_b16_kernel(
    const float* __restrict__ in, unsigned short* __restrict__ outb)
{
    __shared__ float t[64][65];
    const int lane = threadIdx.x & 63, grp = threadIdx.x >> 6;
    const int p0 = blockIdx.x * 64;
    const int c0 = blockIdx.y * 64;
    const int b  = blockIdx.z;
#pragma unroll
    for (int j = 0; j < 16; j++) {
        int c = c0 + j * 4 + grp;
        int p = p0 + lane;
        float v = (p < HW_) ? in[((size_t)(b * C_ + c)) * HW_ + p] : 0.f;
        t[j * 4 + grp][lane] = v;
    }
    __syncthreads();
#pragma unroll
    for (int j = 0; j < 16; j++) {
        int p = p0 + j * 4 + grp;
        int c = c0 + lane;
        if (p < HW_) outb[((size_t)b * HW_ + p) * C_ + c] = f2b(t[lane][j * 4 + grp]);
    }
}

// ------- weight prep (dual): fp32 [co][ci][3][3] -> bf16 [kk][co][ci]; zero stats ----
__global__ void wprep2_kernel(const float* __restrict__ w0, const float* __restrict__ w1,
                              unsigned short* __restrict__ t0, unsigned short* __restrict__ t1,
                              float* __restrict__ stats)
{
    const int co = blockIdx.x, kk = blockIdx.y, tw = blockIdx.z, ci = threadIdx.x;
    const float* w = tw ? w1 : w0;
    unsigned short* t = tw ? t1 : t0;
    t[((size_t)kk * C_ + co) * C_ + ci] = f2b(w[((size_t)co * C_ + ci) * K9 + kk]);
    if (co == 0 && kk == 0 && tw == 0) {
        stats[ci] = 0.f;
        if (ci < 32) stats[256 + ci] = 0.f;   // zbuf
    }
}

// ---------------- MFMA conv3x3 v8: M=128 x N=128, 48KB LDS + T1 (r15 best) ------
__global__ __launch_bounds__(256) void conv3x3_mfma8_kernel(
    const unsigned short* __restrict__ src0, const unsigned short* __restrict__ src1,
    const unsigned short* __restrict__ wtb0, const unsigned short* __restrict__ wtb1,
    const float* __restrict__ bias0, const float* __restrict__ bias1,
    unsigned short* __restrict__ dst0, unsigned short* __restrict__ dst1,
    float* __restrict__ stats, const unsigned short* __restrict__ zbuf, int relu)
{
    __shared__ __align__(16) short a_lds[2][1024 * 8];   // 2 x 16KB
    __shared__ __align__(16) short b_lds[2][512 * 8];    // 2 x 8KB

    const int3 sw = xcd_swizzle();
    const int z = sw.z, b = z & 1, ch = (z >> 1) & 1, tw = z >> 2;
    const unsigned short* act = tw ? src1 : src0;
    const unsigned short* wtb = tw ? wtb1 : wtb0;
    const float* bias = tw ? bias1 : bias0;
    unsigned short* out = tw ? dst1 : dst0;
    float* st = stats ? stats + tw * 128 : nullptr;

    const int tid = threadIdx.x;
    const int lane = tid & 63, wid = tid >> 6;
    const int wr = wid >> 1, wc = wid & 1;       // wr: x-half, wc: co sub-half
    const int l15 = lane & 15, lq = lane >> 4;
    const int x0 = sw.x * 32, y0 = sw.y * 4;

    // ---- A staging sources (4 x 16B units per thread, 1024 units) ----
    const unsigned short* sbaseA[4];
    int sstepA[4];
#pragma unroll
    for (int j = 0; j < 4; j++) {
        int p = j * 256 + tid;                     // physical 16B unit, 0..1023
        int v = p ^ ((p >> 3) & 7);                // logical (involution)
        const unsigned short* src = zbuf;
        int step = 0;
        if (v < 816) {
            int px = v >> 2, q = v & 3;
            int row = px / 34, col = px - row * 34;
            int y = y0 - 1 + row, x = x0 - 1 + col;
            if (y >= 0 && y < H_ && x >= 0 && x < W_) {
                src = act + ((size_t)(b * HW_ + y * W_ + x) * C_ + q * 8);
                step = 1;
            }
        }
        sbaseA[j] = src; sstepA[j] = step;
    }

    // ---- B staging source offsets: physical p -> logical v = p ^ ((p>>3)&3) ----
    int boff[2];
#pragma unroll
    for (int j = 0; j < 2; j++) {
        int p = j * 256 + tid;
        int v = p ^ ((p >> 3) & 3);
        boff[j] = (v >> 2) * 256 + (v & 3) * 8;    // co_local*256 + q*8
    }

    auto STAGE_A = [&](int ci0, int bi) {
#pragma unroll
        for (int j = 0; j < 4; j++)
            load_lds16(sbaseA[j] + sstepA[j] * ci0,
                       &a_lds[bi][(size_t)(j * 256 + tid) * 8]);
    };
    auto STAGE_B = [&](int kk, int ci0, int bi) {
        const unsigned short* wb = wtb + ((size_t)kk * C_ + ch * 128) * C_ + ci0;
#pragma unroll
        for (int j = 0; j < 2; j++)
            load_lds16(wb + boff[j], &b_lds[bi][(size_t)(j * 256 + tid) * 8]);
    };

    f32x4 acc[4][4];
#pragma unroll
    for (int mf = 0; mf < 4; mf++)
#pragma unroll
        for (int nf = 0; nf < 4; nf++) acc[mf][nf] = (f32x4){0.f, 0.f, 0.f, 0.f};

    STAGE_B(0, 0, 0);
    STAGE_A(0, 0);
    asm volatile("s_waitcnt vmcnt(0)" ::: "memory");
    __builtin_amdgcn_s_barrier();

    int bbuf = 0;
    for (int c = 0; c < 8; c++) {
        const int abuf = c & 1;
        const short* ab = a_lds[abuf];
#pragma unroll
        for (int kk = 0; kk < 9; kk++) {
            // ---- issue next-step stages (stay in flight across the barrier) ----
            int issued = 0;
            if (kk < 8)           { STAGE_B(kk + 1, c * 32, bbuf ^ 1); issued += 2; }
            else if (c < 7)       { STAGE_B(0, (c + 1) * 32, bbuf ^ 1); issued += 2; }
            if (kk == 0 && c < 7) { STAGE_A((c + 1) * 32, abuf ^ 1); issued += 4; }
            // T4: retire only PRIOR-step loads; this step's stay outstanding
            if (issued == 6)      asm volatile("s_waitcnt vmcnt(6)" ::: "memory");
            else if (issued == 2) asm volatile("s_waitcnt vmcnt(2)" ::: "memory");
            else                  asm volatile("s_waitcnt vmcnt(0)" ::: "memory");
            __builtin_amdgcn_s_barrier();

            const int ky = kk / 3, kx = kk % 3;
            short8 af[4], bf[4];
#pragma unroll
            for (int mf = 0; mf < 4; mf++) {
                int lv = ((mf + ky) * 34 + wr * 16 + l15 + kx) * 4 + lq;
                int pu = lv ^ ((lv >> 3) & 7);
                af[mf] = *(const short8*)(ab + pu * 8);
            }
            const short* bb = b_lds[bbuf];
#pragma unroll
            for (int nf = 0; nf < 4; nf++) {
                int u  = (wc * 64 + nf * 16 + l15) * 4 + lq;
                int pu = u ^ ((u >> 3) & 3);
                bf[nf] = *(const short8*)(bb + pu * 8);
            }
            __builtin_amdgcn_s_setprio(1);
#pragma unroll
            for (int nf = 0; nf < 4; nf++)
#pragma unroll
                for (int mf = 0; mf < 4; mf++)
                    acc[mf][nf] = __builtin_amdgcn_mfma_f32_16x16x32_bf16(
                        af[mf], bf[nf], acc[mf][nf], 0, 0, 0);
            __builtin_amdgcn_s_setprio(0);
            asm volatile("" ::: "memory");
            __builtin_amdgcn_s_barrier();
            asm volatile("" ::: "memory");
            bbuf ^= 1;
        }
    }

    // ---- epilogue: bias (+relu) store NHWC bf16, fused GN partial stats ----
#pragma unroll
    for (int nf = 0; nf < 4; nf++) {
        int co = ch * 128 + wc * 64 + nf * 16 + l15;
        float bv = bias[co];
        float s = 0.f, ss = 0.f;
#pragma unroll
        for (int mf = 0; mf < 4; mf++) {
            int y = y0 + mf;                        // always < 100 (25 y-tiles)
#pragma unroll
            for (int r = 0; r < 4; r++) {
                int x = x0 + wr * 16 + lq * 4 + r;
                if (x < W_) {
                    float v = acc[mf][nf][r] + bv;
                    s += v; ss += v * v;
                    out[((size_t)(b * HW_ + y * W_ + x)) * C_ + co] =
                        f2b(relu ? fmaxf(v, 0.f) : v);
                }
            }
        }
        if (st) {
            s  += __shfl_xor(s, 1);  ss += __shfl_xor(ss, 1);
            s  += __shfl_xor(s, 2);  ss += __shfl_xor(ss, 2);
            s  += __shfl_xor(s, 4);  ss += __shfl_xor(ss, 4);
            s  += __shfl_xor(s, 16); ss += __shfl_xor(ss, 16);
            s  += __shfl_xor(s, 32); ss += __shfl_xor(ss, 32);
            if ((lane & 55) == 0) {
                int g = co >> 3;
                atomicAdd(&st[(b * 32 + g) * 2],     s);
                atomicAdd(&st[(b * 32 + g) * 2 + 1], ss);
            }
        }
    }
}

// ----- GN apply + ReLU, dual tower, IN PLACE on bf16 NHWC -----
__global__ __launch_bounds__(256) void gn2_apply_kernel(
    unsigned short* __restrict__ buf0, unsigned short* __restrict__ buf1,
    const float* __restrict__ stats,
    const float* __restrict__ g0, const float* __restrict__ be0,
    const float* __restrict__ g1, const float* __restrict__ be1)
{
    const int tw = blockIdx.y;
    unsigned short* buf = tw ? buf1 : buf0;
    const float* gamma = tw ? g1 : g0;
    const float* beta  = tw ? be1 : be0;
    const float* st = stats + tw * 128;

    const int i = blockIdx.x * 256 + threadIdx.x;   // chunk of 8 channels
    const int c8 = i & 31;            // == group id
    const int b = ((i >> 5) >= HW_) ? 1 : 0;
    const float inv_n = 1.f / (8.f * HW_);
    float s1 = st[(b * 32 + c8) * 2];
    float s2 = st[(b * 32 + c8) * 2 + 1];
    float mean = s1 * inv_n;
    float var  = s2 * inv_n - mean * mean;
    float rs = rsqrtf(var + 1e-5f);

    short8 v8 = *(const short8*)(buf + (size_t)i * 8);
    float vo[8];
#pragma unroll
    for (int j = 0; j < 8; j++) {
        int c = c8 * 8 + j;
        float ga = gamma[c] * rs;
        float be = beta[c] - mean * ga;
        vo[j] = fmaxf(fmaf(b2f((unsigned short)v8[j]), ga, be), 0.f);
    }
    unsigned pk[4];
#pragma unroll
    for (int j = 0; j < 4; j++)
        pk[j] = (unsigned)f2b(vo[2 * j]) | ((unsigned)f2b(vo[2 * j + 1]) << 16);
    *(int4*)(buf + (size_t)i * 8) = make_int4(pk[0], pk[1], pk[2], pk[3]);
}

// ---------------- MFMA deformable conv v3: LDS-windowed sampling + T1 ----------
// Single dispatch, grid z=4: b = z&1, tower = z>>1.
__global__ __launch_bounds__(256) void deform3_mfma_kernel(
    const unsigned short* __restrict__ feat0, const unsigned short* __restrict__ feat1,
    const float* __restrict__ pts,
    const unsigned short* __restrict__ wtb0, const unsigned short* __restrict__ wtb1,
    unsigned short* __restrict__ out0, unsigned short* __restrict__ out1,
    const unsigned short* __restrict__ zbuf)
{
    __shared__ __align__(16) short s_lds[32 * 296];   // A-tile [px][kk*32+ci] pad
    __shared__ __align__(16) short f_lds[512 * 8];    // feat window (384 real + pad)
    __shared__ int   p_ref[288][4];
    __shared__ float p_wgt[288][4];

    const int3 sw = xcd_swizzle();
    const int z = sw.z, b = z & 1, tw = z >> 1;
    const unsigned short* feat = tw ? feat1 : feat0;
    const unsigned short* wtb  = tw ? wtb1 : wtb0;
    unsigned short* out        = tw ? out1 : out0;

    const int tid = threadIdx.x;
    const int lane = tid & 63, wc = tid >> 6;
    const int l15 = lane & 15, lq = lane >> 4;
    const int x0 = sw.x * 8, y0 = sw.y * 4;

    // ---- staging sources (2 per thread) for the 8x12 window ----
    const unsigned short* sbase[2];
    int sstep[2];
#pragma unroll
    for (int j = 0; j < 2; j++) {
        int p = (wc + j * 4) * 64 + lane;          // physical unit 0..511
        int v = p ^ ((p >> 3) & 7);                // logical
        const unsigned short* src = zbuf;
        int step = 0;
        if (v < 384) {
            int pix = v >> 2, q = v & 3;
            int wy = pix / 12, wx = pix - wy * 12;
            int y = y0 - 2 + wy, x = x0 - 2 + wx;
            if (y >= 0 && y < H_ && x >= 0 && x < W_) {
                src = feat + ((size_t)(b * HW_ + y * W_ + x) * C_ + q * 8);
                step = 1;
            }
        }
        sbase[j] = src; sstep[j] = step;
    }

    // ---- bilinear setup: 288 (px,tap) pairs ----
    for (int pr = tid; pr < 288; pr += 256) {
        int px_l = pr / 9, kk = pr - px_l * 9;
        int y = y0 + (px_l >> 3), x = x0 + (px_l & 7);
        const float* pb = pts + ((size_t)b * 18 + 2 * kk) * HW_ + y * W_ + x;
        float oy = pb[0], ox = pb[HW_];
        float gy = (float)y + oy, gx = (float)x + ox;
        float fy0 = floorf(gy), fx0 = floorf(gx);
        float dy = gy - fy0, dx = gx - fx0;
        int iy0 = (int)fy0, ix0 = (int)fx0;
        float wy2[2] = {1.f - dy, dy}, wx2[2] = {1.f - dx, dx};
#pragma unroll
        for (int cy = 0; cy < 2; cy++)
#pragma unroll
            for (int cx = 0; cx < 2; cx++) {
                int yy = iy0 + cy, xx = ix0 + cx;
                bool valid = (yy >= 0) && (yy < H_) && (xx >= 0) && (xx < W_);
                int ref = 0;
                float w = 0.f;
                if (valid) {
                    w = wy2[cy] * wx2[cx];
                    int wy = yy - (y0 - 2), wx = xx - (x0 - 2);
                    if (wy >= 0 && wy < 8 && wx >= 0 && wx < 12)
                        ref = wy * 12 + wx;                       // in-window
                    else
                        ref = -(int)((b * HW_ + yy * W_ + xx) * C_) - 1;  // global
                }
                p_ref[pr][cy * 2 + cx] = ref;
                p_wgt[pr][cy * 2 + cx] = w;
            }
    }

    f32x4 acc[2][4];
#pragma unroll
    for (int mf = 0; mf < 2; mf++)
#pragma unroll
        for (int nf = 0; nf < 4; nf++) acc[mf][nf] = (f32x4){0.f, 0.f, 0.f, 0.f};

    auto STAGE = [&](int ci0) {
#pragma unroll
        for (int j = 0; j < 2; j++)
            load_lds16(sbase[j] + sstep[j] * ci0,
                       &f_lds[((wc + j * 4) * 64) * 8]);
    };

    STAGE(0);
    __syncthreads();

    for (int c = 0; c < 8; c++) {
        const int ci0 = c * 32;
        // ---- sample A-tile from LDS window (global fallback if ref<0) ----
        for (int u = tid; u < 1152; u += 256) {
            int q = u & 3, pr = u >> 2;
            int px_l = pr / 9, kk = pr - px_l * 9;
            int4  rf = *(const int4*)p_ref[pr];
            float4 wg = *(const float4*)p_wgt[pr];
            short8 cv[4];
            int rr[4] = {rf.x, rf.y, rf.z, rf.w};
#pragma unroll
            for (int j = 0; j < 4; j++) {
                if (rr[j] >= 0) {
                    int uu = rr[j] * 4 + q;
                    int pu = uu ^ ((uu >> 3) & 7);
                    cv[j] = *(const short8*)(f_lds + pu * 8);
                } else {
                    cv[j] = *(const short8*)(feat + (-rr[j] - 1) + ci0 + q * 8);
                }
            }
            unsigned pk[4];
#pragma unroll
            for (int j = 0; j < 4; j++) {
                float r0 = wg.x * b2f((unsigned short)cv[0][2 * j])
                         + wg.y * b2f((unsigned short)cv[1][2 * j])
                         + wg.z * b2f((unsigned short)cv[2][2 * j])
                         + wg.w * b2f((unsigned short)cv[3][2 * j]);
                float r1 = wg.x * b2f((unsigned short)cv[0][2 * j + 1])
                         + wg.y * b2f((unsigned short)cv[1][2 * j + 1])
                         + wg.z * b2f((unsigned short)cv[2][2 * j + 1])
                         + wg.w * b2f((unsigned short)cv[3][2 * j + 1]);
                asm("v_cvt_pk_bf16_f32 %0, %1, %2" : "=v"(pk[j]) : "v"(r0), "v"(r1));
            }
            *(int4*)(s_lds + px_l * 296 + kk * 32 + q * 8) = make_int4(pk[0], pk[1], pk[2], pk[3]);
        }
        __syncthreads();            // A complete; feat window consumed
        if (c < 7) STAGE(ci0 + 32); // restage window (latency hidden by MFMA)

        // ---- MFMA over 9 taps ----
#pragma unroll
        for (int kk = 0; kk < 9; kk++) {
            short8 af[2];
#pragma unroll
            for (int mf = 0; mf < 2; mf++)
                af[mf] = *(const short8*)(s_lds + (mf * 16 + l15) * 296 + kk * 32 + lq * 8);
#pragma unroll
            for (int nf = 0; nf < 4; nf++) {
                int co = wc * 64 + nf * 16 + l15;
                short8 bf = *(const short8*)(wtb + ((size_t)(kk * C_ + co)) * C_ + ci0 + lq * 8);
#pragma unroll
                for (int mf = 0; mf < 2; mf++)
                    acc[mf][nf] = __builtin_amdgcn_mfma_f32_16x16x32_bf16(
                        af[mf], bf, acc[mf][nf], 0, 0, 0);
            }
        }
        __syncthreads();            // stage drained (vmcnt0); A free
    }

    // ---- epilogue: relu -> bf16 NHWC ----
#pragma unroll
    for (int nf = 0; nf < 4; nf++) {
        int co = wc * 64 + nf * 16 + l15;
#pragma unroll
        for (int mf = 0; mf < 2; mf++) {
#pragma unroll
            for (int r = 0; r < 4; r++) {
                int px_l = mf * 16 + lq * 4 + r;
                int y = y0 + (px_l >> 3), x = x0 + (px_l & 7);
                out[((size_t)(b * HW_ + y * W_ + x)) * C_ + co] =
                    f2b(fmaxf(acc[mf][nf][r], 0.f));
            }
        }
    }
}

// ---------------- 1x1 conv from NHWC bf16 feat, out NCHW fp32 ----------------
template <int NOg>
__global__ __launch_bounds__(256) void conv1x1_kernel(
    const unsigned short* __restrict__ feat, const float* __restrict__ w,
    const float* __restrict__ bias, const float* __restrict__ addsrc,
    float* __restrict__ outp, int O)
{
    const int lane = threadIdx.x & 63, og = threadIdx.x >> 6;
    const int px = blockIdx.x * 64 + lane;
    const int b = (px >= HW_) ? 1 : 0;
    const int rem = px - b * HW_;
    const short8* f8 = (const short8*)(feat + (size_t)px * C_);

    float acc[NOg];
#pragma unroll
    for (int j = 0; j < NOg; j++) acc[j] = 0.f;

    for (int c8 = 0; c8 < 32; c8++) {
        short8 v8 = f8[c8];
        float vf[8];
#pragma unroll
        for (int e = 0; e < 8; e++) vf[e] = b2f((unsigned short)v8[e]);
#pragma unroll
        for (int j = 0; j < NOg; j++) {
            int o = og * NOg + j;
            if (o < O) {
                const float* wr = w + (size_t)o * C_ + c8 * 8;
                float4 w0 = *(const float4*)wr;
                float4 w1 = *(const float4*)(wr + 4);
                acc[j] = fmaf(vf[0], w0.x, acc[j]);
                acc[j] = fmaf(vf[1], w0.y, acc[j]);
                acc[j] = fmaf(vf[2], w0.z, acc[j]);
                acc[j] = fmaf(vf[3], w0.w, acc[j]);
                acc[j] = fmaf(vf[4], w1.x, acc[j]);
                acc[j] = fmaf(vf[5], w1.y, acc[j]);
                acc[j] = fmaf(vf[6], w1.z, acc[j]);
                acc[j] = fmaf(vf[7], w1.w, acc[j]);
            }
        }
    }
#pragma unroll
    for (int j = 0; j < NOg; j++) {
        int o = og * NOg + j;
        if (o < O) {
            float val = acc[j] + bias[o];
            size_t oi = ((size_t)(b * O + o)) * HW_ + rem;
            if (addsrc) val += addsrc[oi];
            outp[oi] = val;
        }
    }
}

// ---------------- host launch ----------------
extern "C" void kernel_launch(void* const* d_in, const int* in_sizes, int n_in,
                              void* d_out, int out_size, void* d_ws, size_t ws_size,
                              hipStream_t stream)
{
    (void)in_sizes; (void)n_in; (void)out_size; (void)ws_size;

    const float* x           = (const float*)d_in[0];
    const float* cls_w       = (const float*)d_in[1];
    const float* cls_b       = (const float*)d_in[2];
    const float* cls_gn_g    = (const float*)d_in[3];
    const float* cls_gn_b    = (const float*)d_in[4];
    const float* reg_w       = (const float*)d_in[5];
    const float* reg_b       = (const float*)d_in[6];
    const float* reg_gn_g    = (const float*)d_in[7];
    const float* reg_gn_b    = (const float*)d_in[8];
    const float* init_conv_w = (const float*)d_in[9];
    const float* init_conv_b = (const float*)d_in[10];
    const float* init_out_w  = (const float*)d_in[11];
    const float* init_out_b  = (const float*)d_in[12];
    const float* cls_dcn_w   = (const float*)d_in[13];
    const float* cls_out_w   = (const float*)d_in[14];
    const float* cls_out_b   = (const float*)d_in[15];
    const float* ref_dcn_w   = (const float*)d_in[16];
    const float* ref_out_w   = (const float*)d_in[17];
    const float* ref_out_b   = (const float*)d_in[18];

    float* out = (float*)d_out;

    const size_t NF = (size_t)B_ * C_ * HW_;   // 7,782,400 elements
    unsigned short* xb16 = (unsigned short*)d_ws;
    unsigned short* bA   = xb16 + NF;
    unsigned short* bB   = bA + NF;
    unsigned short* bC   = bB + NF;
    unsigned short* bD   = bC + NF;
    unsigned short* wtb0 = bD + NF;                    // 589,824 bf16
    unsigned short* wtb1 = wtb0 + (size_t)CK * C_;
    float* stats = (float*)(wtb1 + (size_t)CK * C_);   // 256 stats + 32 zbuf
    const unsigned short* zbuf = (const unsigned short*)(stats + 256);

    const dim3 convGrid2(5, 25, 8);       // dual tower, M=128 x N=128
    const dim3 convGrid1(5, 25, 4);       // single tower (tw=0)
    const dim3 wprepGrid2(C_, 9, 2);
    const dim3 wprepGrid1(C_, 9, 1);
    const dim3 nhwcGrid((HW_ + 63) / 64, C_ / 64, B_);
    const dim3 gnGrid((B_ * HW_ * 32) / 256, 2);
    const dim3 deformGrid(W_ / 8, H_ / 4, 4);        // (19, 25, 4) merged towers
    const int  px_blocks = (B_ * HW_) / 64;          // 475

    to_nhwc_b16_kernel<<<nhwcGrid, 256, 0, stream>>>(x, xb16);

    // --- stage 0: xb16 -> bA (cls), bC (pts) ---
    wprep2_kernel<<<wprepGrid2, 256, 0, stream>>>(cls_w, reg_w, wtb0, wtb1, stats);
    conv3x3_mfma8_kernel<<<convGrid2, 256, 0, stream>>>(
        xb16, xb16, wtb0, wtb1, cls_b, reg_b, bA, bC, stats, zbuf, 0);
    gn2_apply_kernel<<<gnGrid, 256, 0, stream>>>(
        bA, bC, stats, cls_gn_g, cls_gn_b, reg_gn_g, reg_gn_b);

    // --- stage 1: bA -> bB, bC -> bD ---
    wprep2_kernel<<<wprepGrid2, 256, 0, stream>>>(
        cls_w + (size_t)C_ * CK, reg_w + (size_t)C_ * CK, wtb0, wtb1, stats);
    conv3x3_mfma8_kernel<<<convGrid2, 256, 0, stream>>>(
        bA, bC, wtb0, wtb1, cls_b + C_, reg_b + C_, bB, bD, stats, zbuf, 0);
    gn2_apply_kernel<<<gnGrid, 256, 0, stream>>>(
        bB, bD, stats, cls_gn_g + C_, cls_gn_b + C_, reg_gn_g + C_, reg_gn_b + C_);

    // --- stage 2: bB -> bA (clsF), bD -> bC (ptsF) ---
    wprep2_kernel<<<wprepGrid2, 256, 0, stream>>>(
        cls_w + 2 * (size_t)C_ * CK, reg_w + 2 * (size_t)C_ * CK, wtb0, wtb1, stats);
    conv3x3_mfma8_kernel<<<convGrid2, 256, 0, stream>>>(
        bB, bD, wtb0, wtb1, cls_b + 2 * C_, reg_b + 2 * C_, bA, bC, stats, zbuf, 0);
    gn2_apply_kernel<<<gnGrid, 256, 0, stream>>>(
        bA, bC, stats, cls_gn_g + 2 * C_, cls_gn_b + 2 * C_,
        reg_gn_g + 2 * C_, reg_gn_b + 2 * C_);

    // --- init branch: relu(conv3x3(ptsF=bC)) -> bD -> 1x1 -> pts_out_init ---
    wprep2_kernel<<<wprepGrid1, 256, 0, stream>>>(init_conv_w, nullptr, wtb0, nullptr, stats);
    conv3x3_mfma8_kernel<<<convGrid1, 256, 0, stream>>>(
        bC, nullptr, wtb0, nullptr, init_conv_b, nullptr, bD, nullptr, nullptr, zbuf, 1);
    conv1x1_kernel<5><<<px_blocks, 256, 0, stream>>>(
        bD, init_out_w, init_out_b, nullptr, out + OFF_INIT, 18);

    // --- deforms merged into one dispatch (z=4: b, tower) ---
    wprep2_kernel<<<wprepGrid2, 256, 0, stream>>>(cls_dcn_w, ref_dcn_w, wtb0, wtb1, stats);
    deform3_mfma_kernel<<<deformGrid, 256, 0, stream>>>(
        bA, bC, out + OFF_INIT, wtb0, wtb1, bB, bD, zbuf);

    // --- tails ---
    conv1x1_kernel<20><<<px_blocks, 256, 0, stream>>>(
        bB, cls_out_w, cls_out_b, nullptr, out, 80);
    conv1x1_kernel<5><<<px_blocks, 256, 0, stream>>>(
        bD, ref_out_w, ref_out_b, out + OFF_INIT, out + OFF_REF, 18);
}

// Round 18
// 862.589 us; speedup vs baseline: 1.1088x; 1.0666x over previous
//
#include <hip/hip_runtime.h>

// ---------------- problem constants ----------------
constexpr int B_  = 2;
constexpr int C_  = 256;
constexpr int H_  = 100;
constexpr int W_  = 152;
constexpr int HW_ = H_ * W_;          // 15200
constexpr int K9 = 9;
constexpr int CK = C_ * K9;           // 2304

constexpr int OFF_INIT = B_ * 80 * HW_;              // 2,432,000
constexpr int OFF_REF  = OFF_INIT + B_ * 18 * HW_;   // 2,979,200

typedef __attribute__((ext_vector_type(8))) short short8;
typedef __attribute__((ext_vector_type(4))) float f32x4;

__device__ inline unsigned short f2b(float f) {
    union { float f; unsigned u; } x; x.f = f;
    unsigned r = x.u + 0x7fff + ((x.u >> 16) & 1);   // RNE
    return (unsigned short)(r >> 16);
}
__device__ inline float b2f(unsigned short b) {
    union { unsigned u; float f; } x; x.u = ((unsigned)b) << 16; return x.f;
}

__device__ inline void load_lds16(const void* g, void* l) {
    __builtin_amdgcn_global_load_lds(
        (const __attribute__((address_space(1))) unsigned int*)g,
        (__attribute__((address_space(3))) unsigned int*)l, 16, 0, 0);
}

// T1: bijective XCD-aware block swizzle (m204 formula).
__device__ inline int3 xcd_swizzle() {
    const int gx = gridDim.x, gxy = gridDim.x * gridDim.y;
    const int nwg = gxy * gridDim.z;
    int orig = blockIdx.x + gx * blockIdx.y + gxy * blockIdx.z;
    int q = nwg >> 3, r = nwg & 7;
    int xcd = orig & 7, idx = orig >> 3;
    int lg = (xcd < r ? xcd * (q + 1) : r * (q + 1) + (xcd - r) * q) + idx;
    int bz = lg / gxy;
    int rem = lg - bz * gxy;
    int by = rem / gx;
    int bx = rem - by * gx;
    return make_int3(bx, by, bz);
}

// ---------------- NCHW fp32 -> NHWC bf16 (input transform) ----------------
__global__ __launch_bounds__(256) void to_nhwc_b16_kernel(
    const float* __restrict__ in, unsigned short* __restrict__ outb)
{
    __shared__ float t[64][65];
    const int lane = threadIdx.x & 63, grp = threadIdx.x >> 6;
    const int p0 = blockIdx.x * 64;
    const int c0 = blockIdx.y * 64;
    const int b  = blockIdx.z;
#pragma unroll
    for (int j = 0; j < 16; j++) {
        int c = c0 + j * 4 + grp;
        int p = p0 + lane;
        float v = (p < HW_) ? in[((size_t)(b * C_ + c)) * HW_ + p] : 0.f;
        t[j * 4 + grp][lane] = v;
    }
    __syncthreads();
#pragma unroll
    for (int j = 0; j < 16; j++) {
        int p = p0 + j * 4 + grp;
        int c = c0 + lane;
        if (p < HW_) outb[((size_t)b * HW_ + p) * C_ + c] = f2b(t[lane][j * 4 + grp]);
    }
}

// ------- weight prep (dual): fp32 [co][ci][3][3] -> bf16 [kk][co][ci]; zero stats ----
__global__ void wprep2_kernel(const float* __restrict__ w0, const float* __restrict__ w1,
                              unsigned short* __restrict__ t0, unsigned short* __restrict__ t1,
                              float* __restrict__ stats)
{
    const int co = blockIdx.x, kk = blockIdx.y, tw = blockIdx.z, ci = threadIdx.x;
    const float* w = tw ? w1 : w0;
    unsigned short* t = tw ? t1 : t0;
    t[((size_t)kk * C_ + co) * C_ + ci] = f2b(w[((size_t)co * C_ + ci) * K9 + kk]);
    if (co == 0 && kk == 0 && tw == 0) {
        stats[ci] = 0.f;
        if (ci < 32) stats[256 + ci] = 0.f;   // zbuf
    }
}

// ---------------- MFMA conv3x3 v11: M=128 x N=128, 3-deep B, SINGLE barrier ------
// act NHWC bf16; wtb [kk][co][ci] bf16; out NHWC bf16 (pre-norm when stats given).
// Block 256 thr = 4 waves (wr x wc = 2x2); wave tile 64px x 64co; + T1 swizzle.
// 3 B-buffers -> WAR distance 2 -> one s_barrier per K-step (halved vs v8).
// s%3 == kk%3 (9 = 0 mod 3) so all buffer indices are compile-time constants.
// A (2 buffers) staged at kk==0 AFTER the barrier (readers provably done).
__global__ __launch_bounds__(256) void conv3x3_mfma11_kernel(
    const unsigned short* __restrict__ src0, const unsigned short* __restrict__ src1,
    const unsigned short* __restrict__ wtb0, const unsigned short* __restrict__ wtb1,
    const float* __restrict__ bias0, const float* __restrict__ bias1,
    unsigned short* __restrict__ dst0, unsigned short* __restrict__ dst1,
    float* __restrict__ stats, const unsigned short* __restrict__ zbuf, int relu)
{
    __shared__ __align__(16) short a_lds[2][1024 * 8];   // 2 x 16KB
    __shared__ __align__(16) short b_lds[3][512 * 8];    // 3 x 8KB

    const int3 sw = xcd_swizzle();
    const int z = sw.z, b = z & 1, ch = (z >> 1) & 1, tw = z >> 2;
    const unsigned short* act = tw ? src1 : src0;
    const unsigned short* wtb = tw ? wtb1 : wtb0;
    const float* bias = tw ? bias1 : bias0;
    unsigned short* out = tw ? dst1 : dst0;
    float* st = stats ? stats + tw * 128 : nullptr;

    const int tid = threadIdx.x;
    const int lane = tid & 63, wid = tid >> 6;
    const int wr = wid >> 1, wc = wid & 1;       // wr: x-half, wc: co sub-half
    const int l15 = lane & 15, lq = lane >> 4;
    const int x0 = sw.x * 32, y0 = sw.y * 4;

    // ---- A staging sources (4 x 16B units per thread, 1024 units) ----
    const unsigned short* sbaseA[4];
    int sstepA[4];
#pragma unroll
    for (int j = 0; j < 4; j++) {
        int p = j * 256 + tid;                     // physical 16B unit, 0..1023
        int v = p ^ ((p >> 3) & 7);                // logical (involution)
        const unsigned short* src = zbuf;
        int step = 0;
        if (v < 816) {
            int px = v >> 2, q = v & 3;
            int row = px / 34, col = px - row * 34;
            int y = y0 - 1 + row, x = x0 - 1 + col;
            if (y >= 0 && y < H_ && x >= 0 && x < W_) {
                src = act + ((size_t)(b * HW_ + y * W_ + x) * C_ + q * 8);
                step = 1;
            }
        }
        sbaseA[j] = src; sstepA[j] = step;
    }

    // ---- B staging source offsets: physical p -> logical v = p ^ ((p>>3)&3) ----
    int boff[2];
#pragma unroll
    for (int j = 0; j < 2; j++) {
        int p = j * 256 + tid;
        int v = p ^ ((p >> 3) & 3);
        boff[j] = (v >> 2) * 256 + (v & 3) * 8;    // co_local*256 + q*8
    }

    auto STAGE_A = [&](int ci0, int bi) {
#pragma unroll
        for (int j = 0; j < 4; j++)
            load_lds16(sbaseA[j] + sstepA[j] * ci0,
                       &a_lds[bi][(size_t)(j * 256 + tid) * 8]);
    };
    auto STAGE_B = [&](int kk, int ci0, int bi) {
        const unsigned short* wb = wtb + ((size_t)kk * C_ + ch * 128) * C_ + ci0;
#pragma unroll
        for (int j = 0; j < 2; j++)
            load_lds16(wb + boff[j], &b_lds[bi][(size_t)(j * 256 + tid) * 8]);
    };

    f32x4 acc[4][4];
#pragma unroll
    for (int mf = 0; mf < 4; mf++)
#pragma unroll
        for (int nf = 0; nf < 4; nf++) acc[mf][nf] = (f32x4){0.f, 0.f, 0.f, 0.f};

    STAGE_A(0, 0);
    STAGE_B(0, 0, 0);
    asm volatile("s_waitcnt vmcnt(0)" ::: "memory");
    __builtin_amdgcn_s_barrier();

    for (int c = 0; c < 8; c++) {
        const int abuf = c & 1;
        const short* ab = a_lds[abuf];
#pragma unroll
        for (int kk = 0; kk < 9; kk++) {
            // ---- issue next B-stage (pre-barrier; distance-2 WAR safe) ----
            bool bIss = true;
            if (kk < 8)      STAGE_B(kk + 1, c * 32, (kk + 1) % 3);
            else if (c < 7)  STAGE_B(0, (c + 1) * 32, 0);
            else             bIss = false;
            // T4 counted waits: ensure B(s) (and A(c) at kk==0) complete.
            // A(c+1) issued post-barrier at (c,0) -> in flight (4) at (c,1).
            if (kk == 1 && c < 7)  asm volatile("s_waitcnt vmcnt(6)" ::: "memory");
            else if (bIss)         asm volatile("s_waitcnt vmcnt(2)" ::: "memory");
            else                   asm volatile("s_waitcnt vmcnt(0)" ::: "memory");
            __builtin_amdgcn_s_barrier();
            asm volatile("" ::: "memory");
            // A-stage post-barrier: readers of abuf^1 all passed this barrier
            if (kk == 0 && c < 7) STAGE_A((c + 1) * 32, abuf ^ 1);

            const int ky = kk / 3, kx = kk % 3;
            short8 af[4], bf[4];
#pragma unroll
            for (int mf = 0; mf < 4; mf++) {
                int lv = ((mf + ky) * 34 + wr * 16 + l15 + kx) * 4 + lq;
                int pu = lv ^ ((lv >> 3) & 7);
                af[mf] = *(const short8*)(ab + pu * 8);
            }
            const short* bb = b_lds[kk % 3];
#pragma unroll
            for (int nf = 0; nf < 4; nf++) {
                int u  = (wc * 64 + nf * 16 + l15) * 4 + lq;
                int pu = u ^ ((u >> 3) & 3);
                bf[nf] = *(const short8*)(bb + pu * 8);
            }
            __builtin_amdgcn_s_setprio(1);
#pragma unroll
            for (int nf = 0; nf < 4; nf++)
#pragma unroll
                for (int mf = 0; mf < 4; mf++)
                    acc[mf][nf] = __builtin_amdgcn_mfma_f32_16x16x32_bf16(
                        af[mf], bf[nf], acc[mf][nf], 0, 0, 0);
            __builtin_amdgcn_s_setprio(0);
            asm volatile("" ::: "memory");
        }
    }

    // ---- epilogue: bias (+relu) store NHWC bf16, fused GN partial stats ----
#pragma unroll
    for (int nf = 0; nf < 4; nf++) {
        int co = ch * 128 + wc * 64 + nf * 16 + l15;
        float bv = bias[co];
        float s = 0.f, ss = 0.f;
#pragma unroll
        for (int mf = 0; mf < 4; mf++) {
            int y = y0 + mf;                        // always < 100 (25 y-tiles)
#pragma unroll
            for (int r = 0; r < 4; r++) {
                int x = x0 + wr * 16 + lq * 4 + r;
                if (x < W_) {
                    float v = acc[mf][nf][r] + bv;
                    s += v; ss += v * v;
                    out[((size_t)(b * HW_ + y * W_ + x)) * C_ + co] =
                        f2b(relu ? fmaxf(v, 0.f) : v);
                }
            }
        }
        if (st) {
            s  += __shfl_xor(s, 1);  ss += __shfl_xor(ss, 1);
            s  += __shfl_xor(s, 2);  ss += __shfl_xor(ss, 2);
            s  += __shfl_xor(s, 4);  ss += __shfl_xor(ss, 4);
            s  += __shfl_xor(s, 16); ss += __shfl_xor(ss, 16);
            s  += __shfl_xor(s, 32); ss += __shfl_xor(ss, 32);
            if ((lane & 55) == 0) {
                int g = co >> 3;
                atomicAdd(&st[(b * 32 + g) * 2],     s);
                atomicAdd(&st[(b * 32 + g) * 2 + 1], ss);
            }
        }
    }
}

// ----- GN apply + ReLU, dual tower, IN PLACE on bf16 NHWC -----
__global__ __launch_bounds__(256) void gn2_apply_kernel(
    unsigned short* __restrict__ buf0, unsigned short* __restrict__ buf1,
    const float* __restrict__ stats,
    const float* __restrict__ g0, const float* __restrict__ be0,
    const float* __restrict__ g1, const float* __restrict__ be1)
{
    const int tw = blockIdx.y;
    unsigned short* buf = tw ? buf1 : buf0;
    const float* gamma = tw ? g1 : g0;
    const float* beta  = tw ? be1 : be0;
    const float* st = stats + tw * 128;

    const int i = blockIdx.x * 256 + threadIdx.x;   // chunk of 8 channels
    const int c8 = i & 31;            // == group id
    const int b = ((i >> 5) >= HW_) ? 1 : 0;
    const float inv_n = 1.f / (8.f * HW_);
    float s1 = st[(b * 32 + c8) * 2];
    float s2 = st[(b * 32 + c8) * 2 + 1];
    float mean = s1 * inv_n;
    float var  = s2 * inv_n - mean * mean;
    float rs = rsqrtf(var + 1e-5f);

    short8 v8 = *(const short8*)(buf + (size_t)i * 8);
    float vo[8];
#pragma unroll
    for (int j = 0; j < 8; j++) {
        int c = c8 * 8 + j;
        float ga = gamma[c] * rs;
        float be = beta[c] - mean * ga;
        vo[j] = fmaxf(fmaf(b2f((unsigned short)v8[j]), ga, be), 0.f);
    }
    unsigned pk[4];
#pragma unroll
    for (int j = 0; j < 4; j++)
        pk[j] = (unsigned)f2b(vo[2 * j]) | ((unsigned)f2b(vo[2 * j + 1]) << 16);
    *(int4*)(buf + (size_t)i * 8) = make_int4(pk[0], pk[1], pk[2], pk[3]);
}

// ---------------- MFMA deformable conv v3: LDS-windowed sampling + T1 ----------
// Single dispatch, grid z=4: b = z&1, tower = z>>1.
__global__ __launch_bounds__(256) void deform3_mfma_kernel(
    const unsigned short* __restrict__ feat0, const unsigned short* __restrict__ feat1,
    const float* __restrict__ pts,
    const unsigned short* __restrict__ wtb0, const unsigned short* __restrict__ wtb1,
    unsigned short* __restrict__ out0, unsigned short* __restrict__ out1,
    const unsigned short* __restrict__ zbuf)
{
    __shared__ __align__(16) short s_lds[32 * 296];   // A-tile [px][kk*32+ci] pad
    __shared__ __align__(16) short f_lds[512 * 8];    // feat window (384 real + pad)
    __shared__ int   p_ref[288][4];
    __shared__ float p_wgt[288][4];

    const int3 sw = xcd_swizzle();
    const int z = sw.z, b = z & 1, tw = z >> 1;
    const unsigned short* feat = tw ? feat1 : feat0;
    const unsigned short* wtb  = tw ? wtb1 : wtb0;
    unsigned short* out        = tw ? out1 : out0;

    const int tid = threadIdx.x;
    const int lane = tid & 63, wc = tid >> 6;
    const int l15 = lane & 15, lq = lane >> 4;
    const int x0 = sw.x * 8, y0 = sw.y * 4;

    // ---- staging sources (2 per thread) for the 8x12 window ----
    const unsigned short* sbase[2];
    int sstep[2];
#pragma unroll
    for (int j = 0; j < 2; j++) {
        int p = (wc + j * 4) * 64 + lane;          // physical unit 0..511
        int v = p ^ ((p >> 3) & 7);                // logical
        const unsigned short* src = zbuf;
        int step = 0;
        if (v < 384) {
            int pix = v >> 2, q = v & 3;
            int wy = pix / 12, wx = pix - wy * 12;
            int y = y0 - 2 + wy, x = x0 - 2 + wx;
            if (y >= 0 && y < H_ && x >= 0 && x < W_) {
                src = feat + ((size_t)(b * HW_ + y * W_ + x) * C_ + q * 8);
                step = 1;
            }
        }
        sbase[j] = src; sstep[j] = step;
    }

    // ---- bilinear setup: 288 (px,tap) pairs ----
    for (int pr = tid; pr < 288; pr += 256) {
        int px_l = pr / 9, kk = pr - px_l * 9;
        int y = y0 + (px_l >> 3), x = x0 + (px_l & 7);
        const float* pb = pts + ((size_t)b * 18 + 2 * kk) * HW_ + y * W_ + x;
        float oy = pb[0], ox = pb[HW_];
        float gy = (float)y + oy, gx = (float)x + ox;
        float fy0 = floorf(gy), fx0 = floorf(gx);
        float dy = gy - fy0, dx = gx - fx0;
        int iy0 = (int)fy0, ix0 = (int)fx0;
        float wy2[2] = {1.f - dy, dy}, wx2[2] = {1.f - dx, dx};
#pragma unroll
        for (int cy = 0; cy < 2; cy++)
#pragma unroll
            for (int cx = 0; cx < 2; cx++) {
                int yy = iy0 + cy, xx = ix0 + cx;
                bool valid = (yy >= 0) && (yy < H_) && (xx >= 0) && (xx < W_);
                int ref = 0;
                float w = 0.f;
                if (valid) {
                    w = wy2[cy] * wx2[cx];
                    int wy = yy - (y0 - 2), wx = xx - (x0 - 2);
                    if (wy >= 0 && wy < 8 && wx >= 0 && wx < 12)
                        ref = wy * 12 + wx;                       // in-window
                    else
                        ref = -(int)((b * HW_ + yy * W_ + xx) * C_) - 1;  // global
                }
                p_ref[pr][cy * 2 + cx] = ref;
                p_wgt[pr][cy * 2 + cx] = w;
            }
    }

    f32x4 acc[2][4];
#pragma unroll
    for (int mf = 0; mf < 2; mf++)
#pragma unroll
        for (int nf = 0; nf < 4; nf++) acc[mf][nf] = (f32x4){0.f, 0.f, 0.f, 0.f};

    auto STAGE = [&](int ci0) {
#pragma unroll
        for (int j = 0; j < 2; j++)
            load_lds16(sbase[j] + sstep[j] * ci0,
                       &f_lds[((wc + j * 4) * 64) * 8]);
    };

    STAGE(0);
    __syncthreads();

    for (int c = 0; c < 8; c++) {
        const int ci0 = c * 32;
        // ---- sample A-tile from LDS window (global fallback if ref<0) ----
        for (int u = tid; u < 1152; u += 256) {
            int q = u & 3, pr = u >> 2;
            int px_l = pr / 9, kk = pr - px_l * 9;
            int4  rf = *(const int4*)p_ref[pr];
            float4 wg = *(const float4*)p_wgt[pr];
            short8 cv[4];
            int rr[4] = {rf.x, rf.y, rf.z, rf.w};
#pragma unroll
            for (int j = 0; j < 4; j++) {
                if (rr[j] >= 0) {
                    int uu = rr[j] * 4 + q;
                    int pu = uu ^ ((uu >> 3) & 7);
                    cv[j] = *(const short8*)(f_lds + pu * 8);
                } else {
                    cv[j] = *(const short8*)(feat + (-rr[j] - 1) + ci0 + q * 8);
                }
            }
            unsigned pk[4];
#pragma unroll
            for (int j = 0; j < 4; j++) {
                float r0 = wg.x * b2f((unsigned short)cv[0][2 * j])
                         + wg.y * b2f((unsigned short)cv[1][2 * j])
                         + wg.z * b2f((unsigned short)cv[2][2 * j])
                         + wg.w * b2f((unsigned short)cv[3][2 * j]);
                float r1 = wg.x * b2f((unsigned short)cv[0][2 * j + 1])
                         + wg.y * b2f((unsigned short)cv[1][2 * j + 1])
                         + wg.z * b2f((unsigned short)cv[2][2 * j + 1])
                         + wg.w * b2f((unsigned short)cv[3][2 * j + 1]);
                asm("v_cvt_pk_bf16_f32 %0, %1, %2" : "=v"(pk[j]) : "v"(r0), "v"(r1));
            }
            *(int4*)(s_lds + px_l * 296 + kk * 32 + q * 8) = make_int4(pk[0], pk[1], pk[2], pk[3]);
        }
        __syncthreads();            // A complete; feat window consumed
        if (c < 7) STAGE(ci0 + 32); // restage window (latency hidden by MFMA)

        // ---- MFMA over 9 taps ----
#pragma unroll
        for (int kk = 0; kk < 9; kk++) {
            short8 af[2];
#pragma unroll
            for (int mf = 0; mf < 2; mf++)
                af[mf] = *(const short8*)(s_lds + (mf * 16 + l15) * 296 + kk * 32 + lq * 8);
#pragma unroll
            for (int nf = 0; nf < 4; nf++) {
                int co = wc * 64 + nf * 16 + l15;
                short8 bf = *(const short8*)(wtb + ((size_t)(kk * C_ + co)) * C_ + ci0 + lq * 8);
#pragma unroll
                for (int mf = 0; mf < 2; mf++)
                    acc[mf][nf] = __builtin_amdgcn_mfma_f32_16x16x32_bf16(
                        af[mf], bf, acc[mf][nf], 0, 0, 0);
            }
        }
        __syncthreads();            // stage drained (vmcnt0); A free
    }

    // ---- epilogue: relu -> bf16 NHWC ----
#pragma unroll
    for (int nf = 0; nf < 4; nf++) {
        int co = wc * 64 + nf * 16 + l15;
#pragma unroll
        for (int mf = 0; mf < 2; mf++) {
#pragma unroll
            for (int r = 0; r < 4; r++) {
                int px_l = mf * 16 + lq * 4 + r;
                int y = y0 + (px_l >> 3), x = x0 + (px_l & 7);
                out[((size_t)(b * HW_ + y * W_ + x)) * C_ + co] =
                    f2b(fmaxf(acc[mf][nf][r], 0.f));
            }
        }
    }
}

// ---------------- 1x1 conv body from NHWC bf16 feat, out NCHW fp32 ----------------
template <int NOg>
__device__ __forceinline__ void conv1x1_body(
    const unsigned short* __restrict__ feat, const float* __restrict__ w,
    const float* __restrict__ bias, const float* __restrict__ addsrc,
    float* __restrict__ outp, int O)
{
    const int lane = threadIdx.x & 63, og = threadIdx.x >> 6;
    const int px = blockIdx.x * 64 + lane;
    const int b = (px >= HW_) ? 1 : 0;
    const int rem = px - b * HW_;
    const short8* f8 = (const short8*)(feat + (size_t)px * C_);

    float acc[NOg];
#pragma unroll
    for (int j = 0; j < NOg; j++) acc[j] = 0.f;

    for (int c8 = 0; c8 < 32; c8++) {
        short8 v8 = f8[c8];
        float vf[8];
#pragma unroll
        for (int e = 0; e < 8; e++) vf[e] = b2f((unsigned short)v8[e]);
#pragma unroll
        for (int j = 0; j < NOg; j++) {
            int o = og * NOg + j;
            if (o < O) {
                const float* wr = w + (size_t)o * C_ + c8 * 8;
                float4 w0 = *(const float4*)wr;
                float4 w1 = *(const float4*)(wr + 4);
                acc[j] = fmaf(vf[0], w0.x, acc[j]);
                acc[j] = fmaf(vf[1], w0.y, acc[j]);
                acc[j] = fmaf(vf[2], w0.z, acc[j]);
                acc[j] = fmaf(vf[3], w0.w, acc[j]);
                acc[j] = fmaf(vf[4], w1.x, acc[j]);
                acc[j] = fmaf(vf[5], w1.y, acc[j]);
                acc[j] = fmaf(vf[6], w1.z, acc[j]);
                acc[j] = fmaf(vf[7], w1.w, acc[j]);
            }
        }
    }
#pragma unroll
    for (int j = 0; j < NOg; j++) {
        int o = og * NOg + j;
        if (o < O) {
            float val = acc[j] + bias[o];
            size_t oi = ((size_t)(b * O + o)) * HW_ + rem;
            if (addsrc) val += addsrc[oi];
            outp[oi] = val;
        }
    }
}

template <int NOg>
__global__ __launch_bounds__(256) void conv1x1_kernel(
    const unsigned short* __restrict__ feat, const float* __restrict__ w,
    const float* __restrict__ bias, const float* __restrict__ addsrc,
    float* __restrict__ outp, int O)
{
    conv1x1_body<NOg>(feat, w, bias, addsrc, outp, O);
}

// Dual tail: y==0 -> cls head (O=80), y==1 -> refine head (O=18 + addsrc).
__global__ __launch_bounds__(256) void conv1x1_dual_kernel(
    const unsigned short* __restrict__ fA, const float* __restrict__ wA,
    const float* __restrict__ bA_, float* __restrict__ outA,
    const unsigned short* __restrict__ fB, const float* __restrict__ wB,
    const float* __restrict__ bB_, const float* __restrict__ addB,
    float* __restrict__ outB)
{
    if (blockIdx.y == 0) conv1x1_body<20>(fA, wA, bA_, nullptr, outA, 80);
    else                 conv1x1_body<5>(fB, wB, bB_, addB, outB, 18);
}

// ---------------- host launch ----------------
extern "C" void kernel_launch(void* const* d_in, const int* in_sizes, int n_in,
                              void* d_out, int out_size, void* d_ws, size_t ws_size,
                              hipStream_t stream)
{
    (void)in_sizes; (void)n_in; (void)out_size; (void)ws_size;

    const float* x           = (const float*)d_in[0];
    const float* cls_w       = (const float*)d_in[1];
    const float* cls_b       = (const float*)d_in[2];
    const float* cls_gn_g    = (const float*)d_in[3];
    const float* cls_gn_b    = (const float*)d_in[4];
    const float* reg_w       = (const float*)d_in[5];
    const float* reg_b       = (const float*)d_in[6];
    const float* reg_gn_g    = (const float*)d_in[7];
    const float* reg_gn_b    = (const float*)d_in[8];
    const float* init_conv_w = (const float*)d_in[9];
    const float* init_conv_b = (const float*)d_in[10];
    const float* init_out_w  = (const float*)d_in[11];
    const float* init_out_b  = (const float*)d_in[12];
    const float* cls_dcn_w   = (const float*)d_in[13];
    const float* cls_out_w   = (const float*)d_in[14];
    const float* cls_out_b   = (const float*)d_in[15];
    const float* ref_dcn_w   = (const float*)d_in[16];
    const float* ref_out_w   = (const float*)d_in[17];
    const float* ref_out_b   = (const float*)d_in[18];

    float* out = (float*)d_out;

    const size_t NF = (size_t)B_ * C_ * HW_;   // 7,782,400 elements
    unsigned short* xb16 = (unsigned short*)d_ws;
    unsigned short* bA   = xb16 + NF;
    unsigned short* bB   = bA + NF;
    unsigned short* bC   = bB + NF;
    unsigned short* bD   = bC + NF;
    unsigned short* wtb0 = bD + NF;                    // 589,824 bf16
    unsigned short* wtb1 = wtb0 + (size_t)CK * C_;
    float* stats = (float*)(wtb1 + (size_t)CK * C_);   // 256 stats + 32 zbuf
    const unsigned short* zbuf = (const unsigned short*)(stats + 256);

    const dim3 convGrid2(5, 25, 8);       // dual tower, M=128 x N=128
    const dim3 convGrid1(5, 25, 4);       // single tower (tw=0)
    const dim3 wprepGrid2(C_, 9, 2);
    const dim3 wprepGrid1(C_, 9, 1);
    const dim3 nhwcGrid((HW_ + 63) / 64, C_ / 64, B_);
    const dim3 gnGrid((B_ * HW_ * 32) / 256, 2);
    const dim3 deformGrid(W_ / 8, H_ / 4, 4);        // (19, 25, 4) merged towers
    const int  px_blocks = (B_ * HW_) / 64;          // 475
    const dim3 tailGrid(px_blocks, 2);

    to_nhwc_b16_kernel<<<nhwcGrid, 256, 0, stream>>>(x, xb16);

    // --- stage 0: xb16 -> bA (cls), bC (pts) ---
    wprep2_kernel<<<wprepGrid2, 256, 0, stream>>>(cls_w, reg_w, wtb0, wtb1, stats);
    conv3x3_mfma11_kernel<<<convGrid2, 256, 0, stream>>>(
        xb16, xb16, wtb0, wtb1, cls_b, reg_b, bA, bC, stats, zbuf, 0);
    gn2_apply_kernel<<<gnGrid, 256, 0, stream>>>(
        bA, bC, stats, cls_gn_g, cls_gn_b, reg_gn_g, reg_gn_b);

    // --- stage 1: bA -> bB, bC -> bD ---
    wprep2_kernel<<<wprepGrid2, 256, 0, stream>>>(
        cls_w + (size_t)C_ * CK, reg_w + (size_t)C_ * CK, wtb0, wtb1, stats);
    conv3x3_mfma11_kernel<<<convGrid2, 256, 0, stream>>>(
        bA, bC, wtb0, wtb1, cls_b + C_, reg_b + C_, bB, bD, stats, zbuf, 0);
    gn2_apply_kernel<<<gnGrid, 256, 0, stream>>>(
        bB, bD, stats, cls_gn_g + C_, cls_gn_b + C_, reg_gn_g + C_, reg_gn_b + C_);

    // --- stage 2: bB -> bA (clsF), bD -> bC (ptsF) ---
    wprep2_kernel<<<wprepGrid2, 256, 0, stream>>>(
        cls_w + 2 * (size_t)C_ * CK, reg_w + 2 * (size_t)C_ * CK, wtb0, wtb1, stats);
    conv3x3_mfma11_kernel<<<convGrid2, 256, 0, stream>>>(
        bB, bD, wtb0, wtb1, cls_b + 2 * C_, reg_b + 2 * C_, bA, bC, stats, zbuf, 0);
    gn2_apply_kernel<<<gnGrid, 256, 0, stream>>>(
        bA, bC, stats, cls_gn_g + 2 * C_, cls_gn_b + 2 * C_,
        reg_gn_g + 2 * C_, reg_gn_b + 2 * C_);

    // --- init branch: relu(conv3x3(ptsF=bC)) -> bD -> 1x1 -> pts_out_init ---
    wprep2_kernel<<<wprepGrid1, 256, 0, stream>>>(init_conv_w, nullptr, wtb0, nullptr, stats);
    conv3x3_mfma11_kernel<<<convGrid1, 256, 0, stream>>>(
        bC, nullptr, wtb0, nullptr, init_conv_b, nullptr, bD, nullptr, nullptr, zbuf, 1);
    conv1x1_kernel<5><<<px_blocks, 256, 0, stream>>>(
        bD, init_out_w, init_out_b, nullptr, out + OFF_INIT, 18);

    // --- deforms merged into one dispatch (z=4: b, tower) ---
    wprep2_kernel<<<wprepGrid2, 256, 0, stream>>>(cls_dcn_w, ref_dcn_w, wtb0, wtb1, stats);
    deform3_mfma_kernel<<<deformGrid, 256, 0, stream>>>(
        bA, bC, out + OFF_INIT, wtb0, wtb1, bB, bD, zbuf);

    // --- tails merged into one dispatch ---
    conv1x1_dual_kernel<<<tailGrid, 256, 0, stream>>>(
        bB, cls_out_w, cls_out_b, out,
        bD, ref_out_w, ref_out_b, out + OFF_INIT, out + OFF_REF);
}

// Round 19
// 852.444 us; speedup vs baseline: 1.1220x; 1.0119x over previous
//
#include <hip/hip_runtime.h>

// ---------------- problem constants ----------------
constexpr int B_  = 2;
constexpr int C_  = 256;
constexpr int H_  = 100;
constexpr int W_  = 152;
constexpr int HW_ = H_ * W_;          // 15200
constexpr int K9 = 9;
constexpr int CK = C_ * K9;           // 2304
constexpr size_t WSLOT = (size_t)CK * C_;            // 589,824 per weight slot

constexpr int OFF_INIT = B_ * 80 * HW_;              // 2,432,000
constexpr int OFF_REF  = OFF_INIT + B_ * 18 * HW_;   // 2,979,200

typedef __attribute__((ext_vector_type(8))) short short8;
typedef __attribute__((ext_vector_type(4))) float f32x4;

__device__ inline unsigned short f2b(float f) {
    union { float f; unsigned u; } x; x.f = f;
    unsigned r = x.u + 0x7fff + ((x.u >> 16) & 1);   // RNE
    return (unsigned short)(r >> 16);
}
__device__ inline float b2f(unsigned short b) {
    union { unsigned u; float f; } x; x.u = ((unsigned)b) << 16; return x.f;
}

__device__ inline void load_lds16(const void* g, void* l) {
    __builtin_amdgcn_global_load_lds(
        (const __attribute__((address_space(1))) unsigned int*)g,
        (__attribute__((address_space(3))) unsigned int*)l, 16, 0, 0);
}

// T1: bijective XCD-aware block swizzle (m204 formula).
__device__ inline int3 xcd_swizzle() {
    const int gx = gridDim.x, gxy = gridDim.x * gridDim.y;
    const int nwg = gxy * gridDim.z;
    int orig = blockIdx.x + gx * blockIdx.y + gxy * blockIdx.z;
    int q = nwg >> 3, r = nwg & 7;
    int xcd = orig & 7, idx = orig >> 3;
    int lg = (xcd < r ? xcd * (q + 1) : r * (q + 1) + (xcd - r) * q) + idx;
    int bz = lg / gxy;
    int rem = lg - bz * gxy;
    int by = rem / gx;
    int bx = rem - by * gx;
    return make_int3(bx, by, bz);
}

// ---------------- NCHW fp32 -> NHWC bf16 (input transform) ----------------
__global__ __launch_bounds__(256) void to_nhwc_b16_kernel(
    const float* __restrict__ in, unsigned short* __restrict__ outb)
{
    __shared__ float t[64][65];
    const int lane = threadIdx.x & 63, grp = threadIdx.x >> 6;
    const int p0 = blockIdx.x * 64;
    const int c0 = blockIdx.y * 64;
    const int b  = blockIdx.z;
#pragma unroll
    for (int j = 0; j < 16; j++) {
        int c = c0 + j * 4 + grp;
        int p = p0 + lane;
        float v = (p < HW_) ? in[((size_t)(b * C_ + c)) * HW_ + p] : 0.f;
        t[j * 4 + grp][lane] = v;
    }
    __syncthreads();
#pragma unroll
    for (int j = 0; j < 16; j++) {
        int p = p0 + j * 4 + grp;
        int c = c0 + lane;
        if (p < HW_) outb[((size_t)b * HW_ + p) * C_ + c] = f2b(t[lane][j * 4 + grp]);
    }
}

// ---- ALL weight preps in one dispatch: 9 slots -> wtbAll; zero 3 stats bufs ----
// slot 0-2: cls stages; 3-5: reg stages; 6: init; 7: cls_dcn; 8: ref_dcn.
__global__ void wprep_all_kernel(
    const float* __restrict__ cls_w, const float* __restrict__ reg_w,
    const float* __restrict__ init_w, const float* __restrict__ cdcn_w,
    const float* __restrict__ rdcn_w,
    unsigned short* __restrict__ wtbAll, float* __restrict__ statsAll)
{
    const int co = blockIdx.x, kk = blockIdx.y, slot = blockIdx.z, ci = threadIdx.x;
    const float* w;
    if (slot < 3)      w = cls_w + (size_t)slot * C_ * CK;
    else if (slot < 6) w = reg_w + (size_t)(slot - 3) * C_ * CK;
    else if (slot == 6) w = init_w;
    else if (slot == 7) w = cdcn_w;
    else                w = rdcn_w;
    unsigned short* t = wtbAll + (size_t)slot * WSLOT;
    t[((size_t)kk * C_ + co) * C_ + ci] = f2b(w[((size_t)co * C_ + ci) * K9 + kk]);
    if (co == 0 && kk == 0 && slot == 0) {
        statsAll[ci]       = 0.f;
        statsAll[256 + ci] = 0.f;
        statsAll[512 + ci] = 0.f;
        if (ci < 32) statsAll[768 + ci] = 0.f;   // zbuf
    }
}

// ---------------- MFMA conv3x3 v11: M=128 x N=128, 3-deep B, SINGLE barrier ------
__global__ __launch_bounds__(256) void conv3x3_mfma11_kernel(
    const unsigned short* __restrict__ src0, const unsigned short* __restrict__ src1,
    const unsigned short* __restrict__ wtb0, const unsigned short* __restrict__ wtb1,
    const float* __restrict__ bias0, const float* __restrict__ bias1,
    unsigned short* __restrict__ dst0, unsigned short* __restrict__ dst1,
    float* __restrict__ stats, const unsigned short* __restrict__ zbuf, int relu)
{
    __shared__ __align__(16) short a_lds[2][1024 * 8];   // 2 x 16KB
    __shared__ __align__(16) short b_lds[3][512 * 8];    // 3 x 8KB

    const int3 sw = xcd_swizzle();
    const int z = sw.z, b = z & 1, ch = (z >> 1) & 1, tw = z >> 2;
    const unsigned short* act = tw ? src1 : src0;
    const unsigned short* wtb = tw ? wtb1 : wtb0;
    const float* bias = tw ? bias1 : bias0;
    unsigned short* out = tw ? dst1 : dst0;
    float* st = stats ? stats + tw * 128 : nullptr;

    const int tid = threadIdx.x;
    const int lane = tid & 63, wid = tid >> 6;
    const int wr = wid >> 1, wc = wid & 1;       // wr: x-half, wc: co sub-half
    const int l15 = lane & 15, lq = lane >> 4;
    const int x0 = sw.x * 32, y0 = sw.y * 4;

    // ---- A staging sources (4 x 16B units per thread, 1024 units) ----
    const unsigned short* sbaseA[4];
    int sstepA[4];
#pragma unroll
    for (int j = 0; j < 4; j++) {
        int p = j * 256 + tid;                     // physical 16B unit, 0..1023
        int v = p ^ ((p >> 3) & 7);                // logical (involution)
        const unsigned short* src = zbuf;
        int step = 0;
        if (v < 816) {
            int px = v >> 2, q = v & 3;
            int row = px / 34, col = px - row * 34;
            int y = y0 - 1 + row, x = x0 - 1 + col;
            if (y >= 0 && y < H_ && x >= 0 && x < W_) {
                src = act + ((size_t)(b * HW_ + y * W_ + x) * C_ + q * 8);
                step = 1;
            }
        }
        sbaseA[j] = src; sstepA[j] = step;
    }

    // ---- B staging source offsets: physical p -> logical v = p ^ ((p>>3)&3) ----
    int boff[2];
#pragma unroll
    for (int j = 0; j < 2; j++) {
        int p = j * 256 + tid;
        int v = p ^ ((p >> 3) & 3);
        boff[j] = (v >> 2) * 256 + (v & 3) * 8;    // co_local*256 + q*8
    }

    auto STAGE_A = [&](int ci0, int bi) {
#pragma unroll
        for (int j = 0; j < 4; j++)
            load_lds16(sbaseA[j] + sstepA[j] * ci0,
                       &a_lds[bi][(size_t)(j * 256 + tid) * 8]);
    };
    auto STAGE_B = [&](int kk, int ci0, int bi) {
        const unsigned short* wb = wtb + ((size_t)kk * C_ + ch * 128) * C_ + ci0;
#pragma unroll
        for (int j = 0; j < 2; j++)
            load_lds16(wb + boff[j], &b_lds[bi][(size_t)(j * 256 + tid) * 8]);
    };

    f32x4 acc[4][4];
#pragma unroll
    for (int mf = 0; mf < 4; mf++)
#pragma unroll
        for (int nf = 0; nf < 4; nf++) acc[mf][nf] = (f32x4){0.f, 0.f, 0.f, 0.f};

    STAGE_A(0, 0);
    STAGE_B(0, 0, 0);
    asm volatile("s_waitcnt vmcnt(0)" ::: "memory");
    __builtin_amdgcn_s_barrier();

    for (int c = 0; c < 8; c++) {
        const int abuf = c & 1;
        const short* ab = a_lds[abuf];
#pragma unroll
        for (int kk = 0; kk < 9; kk++) {
            // ---- issue next B-stage (pre-barrier; distance-2 WAR safe) ----
            bool bIss = true;
            if (kk < 8)      STAGE_B(kk + 1, c * 32, (kk + 1) % 3);
            else if (c < 7)  STAGE_B(0, (c + 1) * 32, 0);
            else             bIss = false;
            // T4 counted waits: ensure B(s) (and A(c) at kk==0) complete.
            if (kk == 1 && c < 7)  asm volatile("s_waitcnt vmcnt(6)" ::: "memory");
            else if (bIss)         asm volatile("s_waitcnt vmcnt(2)" ::: "memory");
            else                   asm volatile("s_waitcnt vmcnt(0)" ::: "memory");
            __builtin_amdgcn_s_barrier();
            asm volatile("" ::: "memory");
            // A-stage post-barrier: readers of abuf^1 all passed this barrier
            if (kk == 0 && c < 7) STAGE_A((c + 1) * 32, abuf ^ 1);

            const int ky = kk / 3, kx = kk % 3;
            short8 af[4], bf[4];
#pragma unroll
            for (int mf = 0; mf < 4; mf++) {
                int lv = ((mf + ky) * 34 + wr * 16 + l15 + kx) * 4 + lq;
                int pu = lv ^ ((lv >> 3) & 7);
                af[mf] = *(const short8*)(ab + pu * 8);
            }
            const short* bb = b_lds[kk % 3];
#pragma unroll
            for (int nf = 0; nf < 4; nf++) {
                int u  = (wc * 64 + nf * 16 + l15) * 4 + lq;
                int pu = u ^ ((u >> 3) & 3);
                bf[nf] = *(const short8*)(bb + pu * 8);
            }
            __builtin_amdgcn_s_setprio(1);
#pragma unroll
            for (int nf = 0; nf < 4; nf++)
#pragma unroll
                for (int mf = 0; mf < 4; mf++)
                    acc[mf][nf] = __builtin_amdgcn_mfma_f32_16x16x32_bf16(
                        af[mf], bf[nf], acc[mf][nf], 0, 0, 0);
            __builtin_amdgcn_s_setprio(0);
            asm volatile("" ::: "memory");
        }
    }

    // ---- epilogue: bias (+relu) store NHWC bf16, fused GN partial stats ----
#pragma unroll
    for (int nf = 0; nf < 4; nf++) {
        int co = ch * 128 + wc * 64 + nf * 16 + l15;
        float bv = bias[co];
        float s = 0.f, ss = 0.f;
#pragma unroll
        for (int mf = 0; mf < 4; mf++) {
            int y = y0 + mf;                        // always < 100 (25 y-tiles)
#pragma unroll
            for (int r = 0; r < 4; r++) {
                int x = x0 + wr * 16 + lq * 4 + r;
                if (x < W_) {
                    float v = acc[mf][nf][r] + bv;
                    s += v; ss += v * v;
                    out[((size_t)(b * HW_ + y * W_ + x)) * C_ + co] =
                        f2b(relu ? fmaxf(v, 0.f) : v);
                }
            }
        }
        if (st) {
            s  += __shfl_xor(s, 1);  ss += __shfl_xor(ss, 1);
            s  += __shfl_xor(s, 2);  ss += __shfl_xor(ss, 2);
            s  += __shfl_xor(s, 4);  ss += __shfl_xor(ss, 4);
            s  += __shfl_xor(s, 16); ss += __shfl_xor(ss, 16);
            s  += __shfl_xor(s, 32); ss += __shfl_xor(ss, 32);
            if ((lane & 55) == 0) {
                int g = co >> 3;
                atomicAdd(&st[(b * 32 + g) * 2],     s);
                atomicAdd(&st[(b * 32 + g) * 2 + 1], ss);
            }
        }
    }
}

// ----- GN apply + ReLU, dual tower, IN PLACE on bf16 NHWC -----
__global__ __launch_bounds__(256) void gn2_apply_kernel(
    unsigned short* __restrict__ buf0, unsigned short* __restrict__ buf1,
    const float* __restrict__ stats,
    const float* __restrict__ g0, const float* __restrict__ be0,
    const float* __restrict__ g1, const float* __restrict__ be1)
{
    const int tw = blockIdx.y;
    unsigned short* buf = tw ? buf1 : buf0;
    const float* gamma = tw ? g1 : g0;
    const float* beta  = tw ? be1 : be0;
    const float* st = stats + tw * 128;

    const int i = blockIdx.x * 256 + threadIdx.x;   // chunk of 8 channels
    const int c8 = i & 31;            // == group id
    const int b = ((i >> 5) >= HW_) ? 1 : 0;
    const float inv_n = 1.f / (8.f * HW_);
    float s1 = st[(b * 32 + c8) * 2];
    float s2 = st[(b * 32 + c8) * 2 + 1];
    float mean = s1 * inv_n;
    float var  = s2 * inv_n - mean * mean;
    float rs = rsqrtf(var + 1e-5f);

    short8 v8 = *(const short8*)(buf + (size_t)i * 8);
    float vo[8];
#pragma unroll
    for (int j = 0; j < 8; j++) {
        int c = c8 * 8 + j;
        float ga = gamma[c] * rs;
        float be = beta[c] - mean * ga;
        vo[j] = fmaxf(fmaf(b2f((unsigned short)v8[j]), ga, be), 0.f);
    }
    unsigned pk[4];
#pragma unroll
    for (int j = 0; j < 4; j++)
        pk[j] = (unsigned)f2b(vo[2 * j]) | ((unsigned)f2b(vo[2 * j + 1]) << 16);
    *(int4*)(buf + (size_t)i * 8) = make_int4(pk[0], pk[1], pk[2], pk[3]);
}

// ---------------- MFMA deformable conv v3: LDS-windowed sampling + T1 ----------
// Single dispatch, grid z=4: b = z&1, tower = z>>1.
__global__ __launch_bounds__(256) void deform3_mfma_kernel(
    const unsigned short* __restrict__ feat0, const unsigned short* __restrict__ feat1,
    const float* __restrict__ pts,
    const unsigned short* __restrict__ wtb0, const unsigned short* __restrict__ wtb1,
    unsigned short* __restrict__ out0, unsigned short* __restrict__ out1,
    const unsigned short* __restrict__ zbuf)
{
    __shared__ __align__(16) short s_lds[32 * 296];   // A-tile [px][kk*32+ci] pad
    __shared__ __align__(16) short f_lds[512 * 8];    // feat window (384 real + pad)
    __shared__ int   p_ref[288][4];
    __shared__ float p_wgt[288][4];

    const int3 sw = xcd_swizzle();
    const int z = sw.z, b = z & 1, tw = z >> 1;
    const unsigned short* feat = tw ? feat1 : feat0;
    const unsigned short* wtb  = tw ? wtb1 : wtb0;
    unsigned short* out        = tw ? out1 : out0;

    const int tid = threadIdx.x;
    const int lane = tid & 63, wc = tid >> 6;
    const int l15 = lane & 15, lq = lane >> 4;
    const int x0 = sw.x * 8, y0 = sw.y * 4;

    // ---- staging sources (2 per thread) for the 8x12 window ----
    const unsigned short* sbase[2];
    int sstep[2];
#pragma unroll
    for (int j = 0; j < 2; j++) {
        int p = (wc + j * 4) * 64 + lane;          // physical unit 0..511
        int v = p ^ ((p >> 3) & 7);                // logical
        const unsigned short* src = zbuf;
        int step = 0;
        if (v < 384) {
            int pix = v >> 2, q = v & 3;
            int wy = pix / 12, wx = pix - wy * 12;
            int y = y0 - 2 + wy, x = x0 - 2 + wx;
            if (y >= 0 && y < H_ && x >= 0 && x < W_) {
                src = feat + ((size_t)(b * HW_ + y * W_ + x) * C_ + q * 8);
                step = 1;
            }
        }
        sbase[j] = src; sstep[j] = step;
    }

    // ---- bilinear setup: 288 (px,tap) pairs ----
    for (int pr = tid; pr < 288; pr += 256) {
        int px_l = pr / 9, kk = pr - px_l * 9;
        int y = y0 + (px_l >> 3), x = x0 + (px_l & 7);
        const float* pb = pts + ((size_t)b * 18 + 2 * kk) * HW_ + y * W_ + x;
        float oy = pb[0], ox = pb[HW_];
        float gy = (float)y + oy, gx = (float)x + ox;
        float fy0 = floorf(gy), fx0 = floorf(gx);
        float dy = gy - fy0, dx = gx - fx0;
        int iy0 = (int)fy0, ix0 = (int)fx0;
        float wy2[2] = {1.f - dy, dy}, wx2[2] = {1.f - dx, dx};
#pragma unroll
        for (int cy = 0; cy < 2; cy++)
#pragma unroll
            for (int cx = 0; cx < 2; cx++) {
                int yy = iy0 + cy, xx = ix0 + cx;
                bool valid = (yy >= 0) && (yy < H_) && (xx >= 0) && (xx < W_);
                int ref = 0;
                float w = 0.f;
                if (valid) {
                    w = wy2[cy] * wx2[cx];
                    int wy = yy - (y0 - 2), wx = xx - (x0 - 2);
                    if (wy >= 0 && wy < 8 && wx >= 0 && wx < 12)
                        ref = wy * 12 + wx;                       // in-window
                    else
                        ref = -(int)((b * HW_ + yy * W_ + xx) * C_) - 1;  // global
                }
                p_ref[pr][cy * 2 + cx] = ref;
                p_wgt[pr][cy * 2 + cx] = w;
            }
    }

    f32x4 acc[2][4];
#pragma unroll
    for (int mf = 0; mf < 2; mf++)
#pragma unroll
        for (int nf = 0; nf < 4; nf++) acc[mf][nf] = (f32x4){0.f, 0.f, 0.f, 0.f};

    auto STAGE = [&](int ci0) {
#pragma unroll
        for (int j = 0; j < 2; j++)
            load_lds16(sbase[j] + sstep[j] * ci0,
                       &f_lds[((wc + j * 4) * 64) * 8]);
    };

    STAGE(0);
    __syncthreads();

    for (int c = 0; c < 8; c++) {
        const int ci0 = c * 32;
        // ---- sample A-tile from LDS window (global fallback if ref<0) ----
        for (int u = tid; u < 1152; u += 256) {
            int q = u & 3, pr = u >> 2;
            int px_l = pr / 9, kk = pr - px_l * 9;
            int4  rf = *(const int4*)p_ref[pr];
            float4 wg = *(const float4*)p_wgt[pr];
            short8 cv[4];
            int rr[4] = {rf.x, rf.y, rf.z, rf.w};
#pragma unroll
            for (int j = 0; j < 4; j++) {
                if (rr[j] >= 0) {
                    int uu = rr[j] * 4 + q;
                    int pu = uu ^ ((uu >> 3) & 7);
                    cv[j] = *(const short8*)(f_lds + pu * 8);
                } else {
                    cv[j] = *(const short8*)(feat + (-rr[j] - 1) + ci0 + q * 8);
                }
            }
            unsigned pk[4];
#pragma unroll
            for (int j = 0; j < 4; j++) {
                float r0 = wg.x * b2f((unsigned short)cv[0][2 * j])
                         + wg.y * b2f((unsigned short)cv[1][2 * j])
                         + wg.z * b2f((unsigned short)cv[2][2 * j])
                         + wg.w * b2f((unsigned short)cv[3][2 * j]);
                float r1 = wg.x * b2f((unsigned short)cv[0][2 * j + 1])
                         + wg.y * b2f((unsigned short)cv[1][2 * j + 1])
                         + wg.z * b2f((unsigned short)cv[2][2 * j + 1])
                         + wg.w * b2f((unsigned short)cv[3][2 * j + 1]);
                asm("v_cvt_pk_bf16_f32 %0, %1, %2" : "=v"(pk[j]) : "v"(r0), "v"(r1));
            }
            *(int4*)(s_lds + px_l * 296 + kk * 32 + q * 8) = make_int4(pk[0], pk[1], pk[2], pk[3]);
        }
        __syncthreads();            // A complete; feat window consumed
        if (c < 7) STAGE(ci0 + 32); // restage window (latency hidden by MFMA)

        // ---- MFMA over 9 taps ----
#pragma unroll
        for (int kk = 0; kk < 9; kk++) {
            short8 af[2];
#pragma unroll
            for (int mf = 0; mf < 2; mf++)
                af[mf] = *(const short8*)(s_lds + (mf * 16 + l15) * 296 + kk * 32 + lq * 8);
#pragma unroll
            for (int nf = 0; nf < 4; nf++) {
                int co = wc * 64 + nf * 16 + l15;
                short8 bf = *(const short8*)(wtb + ((size_t)(kk * C_ + co)) * C_ + ci0 + lq * 8);
#pragma unroll
                for (int mf = 0; mf < 2; mf++)
                    acc[mf][nf] = __builtin_amdgcn_mfma_f32_16x16x32_bf16(
                        af[mf], bf, acc[mf][nf], 0, 0, 0);
            }
        }
        __syncthreads();            // stage drained (vmcnt0); A free
    }

    // ---- epilogue: relu -> bf16 NHWC ----
#pragma unroll
    for (int nf = 0; nf < 4; nf++) {
        int co = wc * 64 + nf * 16 + l15;
#pragma unroll
        for (int mf = 0; mf < 2; mf++) {
#pragma unroll
            for (int r = 0; r < 4; r++) {
                int px_l = mf * 16 + lq * 4 + r;
                int y = y0 + (px_l >> 3), x = x0 + (px_l & 7);
                out[((size_t)(b * HW_ + y * W_ + x)) * C_ + co] =
                    f2b(fmaxf(acc[mf][nf][r], 0.f));
            }
        }
    }
}

// ---------------- 1x1 conv body from NHWC bf16 feat, out NCHW fp32 ----------------
template <int NOg>
__device__ __forceinline__ void conv1x1_body(
    const unsigned short* __restrict__ feat, const float* __restrict__ w,
    const float* __restrict__ bias, const float* __restrict__ addsrc,
    float* __restrict__ outp, int O)
{
    const int lane = threadIdx.x & 63, og = threadIdx.x >> 6;
    const int px = blockIdx.x * 64 + lane;
    const int b = (px >= HW_) ? 1 : 0;
    const int rem = px - b * HW_;
    const short8* f8 = (const short8*)(feat + (size_t)px * C_);

    float acc[NOg];
#pragma unroll
    for (int j = 0; j < NOg; j++) acc[j] = 0.f;

    for (int c8 = 0; c8 < 32; c8++) {
        short8 v8 = f8[c8];
        float vf[8];
#pragma unroll
        for (int e = 0; e < 8; e++) vf[e] = b2f((unsigned short)v8[e]);
#pragma unroll
        for (int j = 0; j < NOg; j++) {
            int o = og * NOg + j;
            if (o < O) {
                const float* wr = w + (size_t)o * C_ + c8 * 8;
                float4 w0 = *(const float4*)wr;
                float4 w1 = *(const float4*)(wr + 4);
                acc[j] = fmaf(vf[0], w0.x, acc[j]);
                acc[j] = fmaf(vf[1], w0.y, acc[j]);
                acc[j] = fmaf(vf[2], w0.z, acc[j]);
                acc[j] = fmaf(vf[3], w0.w, acc[j]);
                acc[j] = fmaf(vf[4], w1.x, acc[j]);
                acc[j] = fmaf(vf[5], w1.y, acc[j]);
                acc[j] = fmaf(vf[6], w1.z, acc[j]);
                acc[j] = fmaf(vf[7], w1.w, acc[j]);
            }
        }
    }
#pragma unroll
    for (int j = 0; j < NOg; j++) {
        int o = og * NOg + j;
        if (o < O) {
            float val = acc[j] + bias[o];
            size_t oi = ((size_t)(b * O + o)) * HW_ + rem;
            if (addsrc) val += addsrc[oi];
            outp[oi] = val;
        }
    }
}

template <int NOg>
__global__ __launch_bounds__(256) void conv1x1_kernel(
    const unsigned short* __restrict__ feat, const float* __restrict__ w,
    const float* __restrict__ bias, const float* __restrict__ addsrc,
    float* __restrict__ outp, int O)
{
    conv1x1_body<NOg>(feat, w, bias, addsrc, outp, O);
}

// Dual tail: y==0 -> cls head (O=80), y==1 -> refine head (O=18 + addsrc).
__global__ __launch_bounds__(256) void conv1x1_dual_kernel(
    const unsigned short* __restrict__ fA, const float* __restrict__ wA,
    const float* __restrict__ bA_, float* __restrict__ outA,
    const unsigned short* __restrict__ fB, const float* __restrict__ wB,
    const float* __restrict__ bB_, const float* __restrict__ addB,
    float* __restrict__ outB)
{
    if (blockIdx.y == 0) conv1x1_body<20>(fA, wA, bA_, nullptr, outA, 80);
    else                 conv1x1_body<5>(fB, wB, bB_, addB, outB, 18);
}

// ---------------- host launch ----------------
extern "C" void kernel_launch(void* const* d_in, const int* in_sizes, int n_in,
                              void* d_out, int out_size, void* d_ws, size_t ws_size,
                              hipStream_t stream)
{
    (void)in_sizes; (void)n_in; (void)out_size; (void)ws_size;

    const float* x           = (const float*)d_in[0];
    const float* cls_w       = (const float*)d_in[1];
    const float* cls_b       = (const float*)d_in[2];
    const float* cls_gn_g    = (const float*)d_in[3];
    const float* cls_gn_b    = (const float*)d_in[4];
    const float* reg_w       = (const float*)d_in[5];
    const float* reg_b       = (const float*)d_in[6];
    const float* reg_gn_g    = (const float*)d_in[7];
    const float* reg_gn_b    = (const float*)d_in[8];
    const float* init_conv_w = (const float*)d_in[9];
    const float* init_conv_b = (const float*)d_in[10];
    const float* init_out_w  = (const float*)d_in[11];
    const float* init_out_b  = (const float*)d_in[12];
    const float* cls_dcn_w   = (const float*)d_in[13];
    const float* cls_out_w   = (const float*)d_in[14];
    const float* cls_out_b   = (const float*)d_in[15];
    const float* ref_dcn_w   = (const float*)d_in[16];
    const float* ref_out_w   = (const float*)d_in[17];
    const float* ref_out_b   = (const float*)d_in[18];

    float* out = (float*)d_out;

    const size_t NF = (size_t)B_ * C_ * HW_;   // 7,782,400 elements
    unsigned short* xb16   = (unsigned short*)d_ws;
    unsigned short* bA     = xb16 + NF;
    unsigned short* bB     = bA + NF;
    unsigned short* bC     = bB + NF;
    unsigned short* bD     = bC + NF;
    unsigned short* wtbAll = bD + NF;                    // 9 x 589,824 bf16
    float* statsAll = (float*)(wtbAll + 9 * WSLOT);      // 3x256 stats + 32 zbuf
    const unsigned short* zbuf = (const unsigned short*)(statsAll + 768);

    const dim3 convGrid2(5, 25, 8);       // dual tower, M=128 x N=128
    const dim3 convGrid1(5, 25, 4);       // single tower (tw=0)
    const dim3 wprepGridAll(C_, 9, 9);
    const dim3 nhwcGrid((HW_ + 63) / 64, C_ / 64, B_);
    const dim3 gnGrid((B_ * HW_ * 32) / 256, 2);
    const dim3 deformGrid(W_ / 8, H_ / 4, 4);        // (19, 25, 4) merged towers
    const int  px_blocks = (B_ * HW_) / 64;          // 475
    const dim3 tailGrid(px_blocks, 2);

    // --- all weight preps + stats zeroing, one dispatch up front ---
    wprep_all_kernel<<<wprepGridAll, 256, 0, stream>>>(
        cls_w, reg_w, init_conv_w, cls_dcn_w, ref_dcn_w, wtbAll, statsAll);
    to_nhwc_b16_kernel<<<nhwcGrid, 256, 0, stream>>>(x, xb16);

    // --- stage 0: xb16 -> bA (cls), bC (pts) ---
    conv3x3_mfma11_kernel<<<convGrid2, 256, 0, stream>>>(
        xb16, xb16, wtbAll, wtbAll + 3 * WSLOT, cls_b, reg_b, bA, bC,
        statsAll, zbuf, 0);
    gn2_apply_kernel<<<gnGrid, 256, 0, stream>>>(
        bA, bC, statsAll, cls_gn_g, cls_gn_b, reg_gn_g, reg_gn_b);

    // --- stage 1: bA -> bB, bC -> bD ---
    conv3x3_mfma11_kernel<<<convGrid2, 256, 0, stream>>>(
        bA, bC, wtbAll + 1 * WSLOT, wtbAll + 4 * WSLOT, cls_b + C_, reg_b + C_,
        bB, bD, statsAll + 256, zbuf, 0);
    gn2_apply_kernel<<<gnGrid, 256, 0, stream>>>(
        bB, bD, statsAll + 256, cls_gn_g + C_, cls_gn_b + C_,
        reg_gn_g + C_, reg_gn_b + C_);

    // --- stage 2: bB -> bA (clsF), bD -> bC (ptsF) ---
    conv3x3_mfma11_kernel<<<convGrid2, 256, 0, stream>>>(
        bB, bD, wtbAll + 2 * WSLOT, wtbAll + 5 * WSLOT, cls_b + 2 * C_,
        reg_b + 2 * C_, bA, bC, statsAll + 512, zbuf, 0);
    gn2_apply_kernel<<<gnGrid, 256, 0, stream>>>(
        bA, bC, statsAll + 512, cls_gn_g + 2 * C_, cls_gn_b + 2 * C_,
        reg_gn_g + 2 * C_, reg_gn_b + 2 * C_);

    // --- init branch: relu(conv3x3(ptsF=bC)) -> bD -> 1x1 -> pts_out_init ---
    conv3x3_mfma11_kernel<<<convGrid1, 256, 0, stream>>>(
        bC, nullptr, wtbAll + 6 * WSLOT, nullptr, init_conv_b, nullptr,
        bD, nullptr, nullptr, zbuf, 1);
    conv1x1_kernel<5><<<px_blocks, 256, 0, stream>>>(
        bD, init_out_w, init_out_b, nullptr, out + OFF_INIT, 18);

    // --- deforms merged into one dispatch (z=4: b, tower) ---
    deform3_mfma_kernel<<<deformGrid, 256, 0, stream>>>(
        bA, bC, out + OFF_INIT, wtbAll + 7 * WSLOT, wtbAll + 8 * WSLOT,
        bB, bD, zbuf);

    // --- tails merged into one dispatch ---
    conv1x1_dual_kernel<<<tailGrid, 256, 0, stream>>>(
        bB, cls_out_w, cls_out_b, out,
        bD, ref_out_w, ref_out_b, out + OFF_INIT, out + OFF_REF);
}

// Round 20
// 849.601 us; speedup vs baseline: 1.1258x; 1.0033x over previous
//
#include <hip/hip_runtime.h>

// ---------------- problem constants ----------------
constexpr int B_  = 2;
constexpr int C_  = 256;
constexpr int H_  = 100;
constexpr int W_  = 152;
constexpr int HW_ = H_ * W_;          // 15200
constexpr int K9 = 9;
constexpr int CK = C_ * K9;           // 2304
constexpr size_t WSLOT = (size_t)CK * C_;            // 589,824 per weight slot

constexpr int OFF_INIT = B_ * 80 * HW_;              // 2,432,000
constexpr int OFF_REF  = OFF_INIT + B_ * 18 * HW_;   // 2,979,200

typedef __attribute__((ext_vector_type(8))) short short8;
typedef __attribute__((ext_vector_type(4))) float f32x4;

__device__ inline unsigned short f2b(float f) {
    union { float f; unsigned u; } x; x.f = f;
    unsigned r = x.u + 0x7fff + ((x.u >> 16) & 1);   // RNE
    return (unsigned short)(r >> 16);
}
__device__ inline float b2f(unsigned short b) {
    union { unsigned u; float f; } x; x.u = ((unsigned)b) << 16; return x.f;
}

__device__ inline void load_lds16(const void* g, void* l) {
    __builtin_amdgcn_global_load_lds(
        (const __attribute__((address_space(1))) unsigned int*)g,
        (__attribute__((address_space(3))) unsigned int*)l, 16, 0, 0);
}

// T1: bijective XCD-aware block swizzle (m204 formula).
__device__ inline int3 xcd_swizzle() {
    const int gx = gridDim.x, gxy = gridDim.x * gridDim.y;
    const int nwg = gxy * gridDim.z;
    int orig = blockIdx.x + gx * blockIdx.y + gxy * blockIdx.z;
    int q = nwg >> 3, r = nwg & 7;
    int xcd = orig & 7, idx = orig >> 3;
    int lg = (xcd < r ? xcd * (q + 1) : r * (q + 1) + (xcd - r) * q) + idx;
    int bz = lg / gxy;
    int rem = lg - bz * gxy;
    int by = rem / gx;
    int bx = rem - by * gx;
    return make_int3(bx, by, bz);
}

// ---------------- NCHW fp32 -> NHWC bf16 (input transform) ----------------
__global__ __launch_bounds__(256) void to_nhwc_b16_kernel(
    const float* __restrict__ in, unsigned short* __restrict__ outb)
{
    __shared__ float t[64][65];
    const int lane = threadIdx.x & 63, grp = threadIdx.x >> 6;
    const int p0 = blockIdx.x * 64;
    const int c0 = blockIdx.y * 64;
    const int b  = blockIdx.z;
#pragma unroll
    for (int j = 0; j < 16; j++) {
        int c = c0 + j * 4 + grp;
        int p = p0 + lane;
        float v = (p < HW_) ? in[((size_t)(b * C_ + c)) * HW_ + p] : 0.f;
        t[j * 4 + grp][lane] = v;
    }
    __syncthreads();
#pragma unroll
    for (int j = 0; j < 16; j++) {
        int p = p0 + j * 4 + grp;
        int c = c0 + lane;
        if (p < HW_) outb[((size_t)b * HW_ + p) * C_ + c] = f2b(t[lane][j * 4 + grp]);
    }
}

// ---- ALL weight preps in one dispatch: 9 slots -> wtbAll; zero 3 stats bufs ----
// slot 0-2: cls stages; 3-5: reg stages; 6: init; 7: cls_dcn; 8: ref_dcn.
__global__ void wprep_all_kernel(
    const float* __restrict__ cls_w, const float* __restrict__ reg_w,
    const float* __restrict__ init_w, const float* __restrict__ cdcn_w,
    const float* __restrict__ rdcn_w,
    unsigned short* __restrict__ wtbAll, float* __restrict__ statsAll)
{
    const int co = blockIdx.x, kk = blockIdx.y, slot = blockIdx.z, ci = threadIdx.x;
    const float* w;
    if (slot < 3)      w = cls_w + (size_t)slot * C_ * CK;
    else if (slot < 6) w = reg_w + (size_t)(slot - 3) * C_ * CK;
    else if (slot == 6) w = init_w;
    else if (slot == 7) w = cdcn_w;
    else                w = rdcn_w;
    unsigned short* t = wtbAll + (size_t)slot * WSLOT;
    t[((size_t)kk * C_ + co) * C_ + ci] = f2b(w[((size_t)co * C_ + ci) * K9 + kk]);
    if (co == 0 && kk == 0 && slot == 0) {
        statsAll[ci]       = 0.f;
        statsAll[256 + ci] = 0.f;
        statsAll[512 + ci] = 0.f;
        if (ci < 32) statsAll[768 + ci] = 0.f;   // zbuf
    }
}

// ---------------- MFMA conv3x3 v12: v11 + ch folded into x (act read once/XCD) ---
// grid (10, 25, nz): sw.x = xt*2 + ch; z = (tw<<1)|b. T1's contiguous-orig runs
// now co-locate both co-halves of a tile on one XCD -> act HBM traffic ~halves.
__global__ __launch_bounds__(256) void conv3x3_mfma12_kernel(
    const unsigned short* __restrict__ src0, const unsigned short* __restrict__ src1,
    const unsigned short* __restrict__ wtb0, const unsigned short* __restrict__ wtb1,
    const float* __restrict__ bias0, const float* __restrict__ bias1,
    unsigned short* __restrict__ dst0, unsigned short* __restrict__ dst1,
    float* __restrict__ stats, const unsigned short* __restrict__ zbuf, int relu)
{
    __shared__ __align__(16) short a_lds[2][1024 * 8];   // 2 x 16KB
    __shared__ __align__(16) short b_lds[3][512 * 8];    // 3 x 8KB

    const int3 sw = xcd_swizzle();
    const int z = sw.z, b = z & 1, tw = z >> 1;
    const int ch = sw.x & 1, xt = sw.x >> 1;
    const unsigned short* act = tw ? src1 : src0;
    const unsigned short* wtb = tw ? wtb1 : wtb0;
    const float* bias = tw ? bias1 : bias0;
    unsigned short* out = tw ? dst1 : dst0;
    float* st = stats ? stats + tw * 128 : nullptr;

    const int tid = threadIdx.x;
    const int lane = tid & 63, wid = tid >> 6;
    const int wr = wid >> 1, wc = wid & 1;       // wr: x-half, wc: co sub-half
    const int l15 = lane & 15, lq = lane >> 4;
    const int x0 = xt * 32, y0 = sw.y * 4;

    // ---- A staging sources (4 x 16B units per thread, 1024 units) ----
    const unsigned short* sbaseA[4];
    int sstepA[4];
#pragma unroll
    for (int j = 0; j < 4; j++) {
        int p = j * 256 + tid;                     // physical 16B unit, 0..1023
        int v = p ^ ((p >> 3) & 7);                // logical (involution)
        const unsigned short* src = zbuf;
        int step = 0;
        if (v < 816) {
            int px = v >> 2, q = v & 3;
            int row = px / 34, col = px - row * 34;
            int y = y0 - 1 + row, x = x0 - 1 + col;
            if (y >= 0 && y < H_ && x >= 0 && x < W_) {
                src = act + ((size_t)(b * HW_ + y * W_ + x) * C_ + q * 8);
                step = 1;
            }
        }
        sbaseA[j] = src; sstepA[j] = step;
    }

    // ---- B staging source offsets: physical p -> logical v = p ^ ((p>>3)&3) ----
    int boff[2];
#pragma unroll
    for (int j = 0; j < 2; j++) {
        int p = j * 256 + tid;
        int v = p ^ ((p >> 3) & 3);
        boff[j] = (v >> 2) * 256 + (v & 3) * 8;    // co_local*256 + q*8
    }

    auto STAGE_A = [&](int ci0, int bi) {
#pragma unroll
        for (int j = 0; j < 4; j++)
            load_lds16(sbaseA[j] + sstepA[j] * ci0,
                       &a_lds[bi][(size_t)(j * 256 + tid) * 8]);
    };
    auto STAGE_B = [&](int kk, int ci0, int bi) {
        const unsigned short* wb = wtb + ((size_t)kk * C_ + ch * 128) * C_ + ci0;
#pragma unroll
        for (int j = 0; j < 2; j++)
            load_lds16(wb + boff[j], &b_lds[bi][(size_t)(j * 256 + tid) * 8]);
    };

    f32x4 acc[4][4];
#pragma unroll
    for (int mf = 0; mf < 4; mf++)
#pragma unroll
        for (int nf = 0; nf < 4; nf++) acc[mf][nf] = (f32x4){0.f, 0.f, 0.f, 0.f};

    STAGE_A(0, 0);
    STAGE_B(0, 0, 0);
    asm volatile("s_waitcnt vmcnt(0)" ::: "memory");
    __builtin_amdgcn_s_barrier();

    for (int c = 0; c < 8; c++) {
        const int abuf = c & 1;
        const short* ab = a_lds[abuf];
#pragma unroll
        for (int kk = 0; kk < 9; kk++) {
            // ---- issue next B-stage (pre-barrier; distance-2 WAR safe) ----
            bool bIss = true;
            if (kk < 8)      STAGE_B(kk + 1, c * 32, (kk + 1) % 3);
            else if (c < 7)  STAGE_B(0, (c + 1) * 32, 0);
            else             bIss = false;
            // T4 counted waits: ensure B(s) (and A(c) at kk==0) complete.
            if (kk == 1 && c < 7)  asm volatile("s_waitcnt vmcnt(6)" ::: "memory");
            else if (bIss)         asm volatile("s_waitcnt vmcnt(2)" ::: "memory");
            else                   asm volatile("s_waitcnt vmcnt(0)" ::: "memory");
            __builtin_amdgcn_s_barrier();
            asm volatile("" ::: "memory");
            // A-stage post-barrier: readers of abuf^1 all passed this barrier
            if (kk == 0 && c < 7) STAGE_A((c + 1) * 32, abuf ^ 1);

            const int ky = kk / 3, kx = kk % 3;
            short8 af[4], bf[4];
#pragma unroll
            for (int mf = 0; mf < 4; mf++) {
                int lv = ((mf + ky) * 34 + wr * 16 + l15 + kx) * 4 + lq;
                int pu = lv ^ ((lv >> 3) & 7);
                af[mf] = *(const short8*)(ab + pu * 8);
            }
            const short* bb = b_lds[kk % 3];
#pragma unroll
            for (int nf = 0; nf < 4; nf++) {
                int u  = (wc * 64 + nf * 16 + l15) * 4 + lq;
                int pu = u ^ ((u >> 3) & 3);
                bf[nf] = *(const short8*)(bb + pu * 8);
            }
            __builtin_amdgcn_s_setprio(1);
#pragma unroll
            for (int nf = 0; nf < 4; nf++)
#pragma unroll
                for (int mf = 0; mf < 4; mf++)
                    acc[mf][nf] = __builtin_amdgcn_mfma_f32_16x16x32_bf16(
                        af[mf], bf[nf], acc[mf][nf], 0, 0, 0);
            __builtin_amdgcn_s_setprio(0);
            asm volatile("" ::: "memory");
        }
    }

    // ---- epilogue: bias (+relu) store NHWC bf16, fused GN partial stats ----
#pragma unroll
    for (int nf = 0; nf < 4; nf++) {
        int co = ch * 128 + wc * 64 + nf * 16 + l15;
        float bv = bias[co];
        float s = 0.f, ss = 0.f;
#pragma unroll
        for (int mf = 0; mf < 4; mf++) {
            int y = y0 + mf;                        // always < 100 (25 y-tiles)
#pragma unroll
            for (int r = 0; r < 4; r++) {
                int x = x0 + wr * 16 + lq * 4 + r;
                if (x < W_) {
                    float v = acc[mf][nf][r] + bv;
                    s += v; ss += v * v;
                    out[((size_t)(b * HW_ + y * W_ + x)) * C_ + co] =
                        f2b(relu ? fmaxf(v, 0.f) : v);
                }
            }
        }
        if (st) {
            s  += __shfl_xor(s, 1);  ss += __shfl_xor(ss, 1);
            s  += __shfl_xor(s, 2);  ss += __shfl_xor(ss, 2);
            s  += __shfl_xor(s, 4);  ss += __shfl_xor(ss, 4);
            s  += __shfl_xor(s, 16); ss += __shfl_xor(ss, 16);
            s  += __shfl_xor(s, 32); ss += __shfl_xor(ss, 32);
            if ((lane & 55) == 0) {
                int g = co >> 3;
                atomicAdd(&st[(b * 32 + g) * 2],     s);
                atomicAdd(&st[(b * 32 + g) * 2 + 1], ss);
            }
        }
    }
}

// ----- GN apply + ReLU, dual tower, IN PLACE on bf16 NHWC -----
__global__ __launch_bounds__(256) void gn2_apply_kernel(
    unsigned short* __restrict__ buf0, unsigned short* __restrict__ buf1,
    const float* __restrict__ stats,
    const float* __restrict__ g0, const float* __restrict__ be0,
    const float* __restrict__ g1, const float* __restrict__ be1)
{
    const int tw = blockIdx.y;
    unsigned short* buf = tw ? buf1 : buf0;
    const float* gamma = tw ? g1 : g0;
    const float* beta  = tw ? be1 : be0;
    const float* st = stats + tw * 128;

    const int i = blockIdx.x * 256 + threadIdx.x;   // chunk of 8 channels
    const int c8 = i & 31;            // == group id
    const int b = ((i >> 5) >= HW_) ? 1 : 0;
    const float inv_n = 1.f / (8.f * HW_);
    float s1 = st[(b * 32 + c8) * 2];
    float s2 = st[(b * 32 + c8) * 2 + 1];
    float mean = s1 * inv_n;
    float var  = s2 * inv_n - mean * mean;
    float rs = rsqrtf(var + 1e-5f);

    short8 v8 = *(const short8*)(buf + (size_t)i * 8);
    float vo[8];
#pragma unroll
    for (int j = 0; j < 8; j++) {
        int c = c8 * 8 + j;
        float ga = gamma[c] * rs;
        float be = beta[c] - mean * ga;
        vo[j] = fmaxf(fmaf(b2f((unsigned short)v8[j]), ga, be), 0.f);
    }
    unsigned pk[4];
#pragma unroll
    for (int j = 0; j < 4; j++)
        pk[j] = (unsigned)f2b(vo[2 * j]) | ((unsigned)f2b(vo[2 * j + 1]) << 16);
    *(int4*)(buf + (size_t)i * 8) = make_int4(pk[0], pk[1], pk[2], pk[3]);
}

// ---------------- MFMA deformable conv v3: LDS-windowed sampling + T1 ----------
// Single dispatch, grid z=4: b = z&1, tower = z>>1.
__global__ __launch_bounds__(256) void deform3_mfma_kernel(
    const unsigned short* __restrict__ feat0, const unsigned short* __restrict__ feat1,
    const float* __restrict__ pts,
    const unsigned short* __restrict__ wtb0, const unsigned short* __restrict__ wtb1,
    unsigned short* __restrict__ out0, unsigned short* __restrict__ out1,
    const unsigned short* __restrict__ zbuf)
{
    __shared__ __align__(16) short s_lds[32 * 296];   // A-tile [px][kk*32+ci] pad
    __shared__ __align__(16) short f_lds[512 * 8];    // feat window (384 real + pad)
    __shared__ int   p_ref[288][4];
    __shared__ float p_wgt[288][4];

    const int3 sw = xcd_swizzle();
    const int z = sw.z, b = z & 1, tw = z >> 1;
    const unsigned short* feat = tw ? feat1 : feat0;
    const unsigned short* wtb  = tw ? wtb1 : wtb0;
    unsigned short* out        = tw ? out1 : out0;

    const int tid = threadIdx.x;
    const int lane = tid & 63, wc = tid >> 6;
    const int l15 = lane & 15, lq = lane >> 4;
    const int x0 = sw.x * 8, y0 = sw.y * 4;

    // ---- staging sources (2 per thread) for the 8x12 window ----
    const unsigned short* sbase[2];
    int sstep[2];
#pragma unroll
    for (int j = 0; j < 2; j++) {
        int p = (wc + j * 4) * 64 + lane;          // physical unit 0..511
        int v = p ^ ((p >> 3) & 7);                // logical
        const unsigned short* src = zbuf;
        int step = 0;
        if (v < 384) {
            int pix = v >> 2, q = v & 3;
            int wy = pix / 12, wx = pix - wy * 12;
            int y = y0 - 2 + wy, x = x0 - 2 + wx;
            if (y >= 0 && y < H_ && x >= 0 && x < W_) {
                src = feat + ((size_t)(b * HW_ + y * W_ + x) * C_ + q * 8);
                step = 1;
            }
        }
        sbase[j] = src; sstep[j] = step;
    }

    // ---- bilinear setup: 288 (px,tap) pairs ----
    for (int pr = tid; pr < 288; pr += 256) {
        int px_l = pr / 9, kk = pr - px_l * 9;
        int y = y0 + (px_l >> 3), x = x0 + (px_l & 7);
        const float* pb = pts + ((size_t)b * 18 + 2 * kk) * HW_ + y * W_ + x;
        float oy = pb[0], ox = pb[HW_];
        float gy = (float)y + oy, gx = (float)x + ox;
        float fy0 = floorf(gy), fx0 = floorf(gx);
        float dy = gy - fy0, dx = gx - fx0;
        int iy0 = (int)fy0, ix0 = (int)fx0;
        float wy2[2] = {1.f - dy, dy}, wx2[2] = {1.f - dx, dx};
#pragma unroll
        for (int cy = 0; cy < 2; cy++)
#pragma unroll
            for (int cx = 0; cx < 2; cx++) {
                int yy = iy0 + cy, xx = ix0 + cx;
                bool valid = (yy >= 0) && (yy < H_) && (xx >= 0) && (xx < W_);
                int ref = 0;
                float w = 0.f;
                if (valid) {
                    w = wy2[cy] * wx2[cx];
                    int wy = yy - (y0 - 2), wx = xx - (x0 - 2);
                    if (wy >= 0 && wy < 8 && wx >= 0 && wx < 12)
                        ref = wy * 12 + wx;                       // in-window
                    else
                        ref = -(int)((b * HW_ + yy * W_ + xx) * C_) - 1;  // global
                }
                p_ref[pr][cy * 2 + cx] = ref;
                p_wgt[pr][cy * 2 + cx] = w;
            }
    }

    f32x4 acc[2][4];
#pragma unroll
    for (int mf = 0; mf < 2; mf++)
#pragma unroll
        for (int nf = 0; nf < 4; nf++) acc[mf][nf] = (f32x4){0.f, 0.f, 0.f, 0.f};

    auto STAGE = [&](int ci0) {
#pragma unroll
        for (int j = 0; j < 2; j++)
            load_lds16(sbase[j] + sstep[j] * ci0,
                       &f_lds[((wc + j * 4) * 64) * 8]);
    };

    STAGE(0);
    __syncthreads();

    for (int c = 0; c < 8; c++) {
        const int ci0 = c * 32;
        // ---- sample A-tile from LDS window (global fallback if ref<0) ----
        for (int u = tid; u < 1152; u += 256) {
            int q = u & 3, pr = u >> 2;
            int px_l = pr / 9, kk = pr - px_l * 9;
            int4  rf = *(const int4*)p_ref[pr];
            float4 wg = *(const float4*)p_wgt[pr];
            short8 cv[4];
            int rr[4] = {rf.x, rf.y, rf.z, rf.w};
#pragma unroll
            for (int j = 0; j < 4; j++) {
                if (rr[j] >= 0) {
                    int uu = rr[j] * 4 + q;
                    int pu = uu ^ ((uu >> 3) & 7);
                    cv[j] = *(const short8*)(f_lds + pu * 8);
                } else {
                    cv[j] = *(const short8*)(feat + (-rr[j] - 1) + ci0 + q * 8);
                }
            }
            unsigned pk[4];
#pragma unroll
            for (int j = 0; j < 4; j++) {
                float r0 = wg.x * b2f((unsigned short)cv[0][2 * j])
                         + wg.y * b2f((unsigned short)cv[1][2 * j])
                         + wg.z * b2f((unsigned short)cv[2][2 * j])
                         + wg.w * b2f((unsigned short)cv[3][2 * j]);
                float r1 = wg.x * b2f((unsigned short)cv[0][2 * j + 1])
                         + wg.y * b2f((unsigned short)cv[1][2 * j + 1])
                         + wg.z * b2f((unsigned short)cv[2][2 * j + 1])
                         + wg.w * b2f((unsigned short)cv[3][2 * j + 1]);
                asm("v_cvt_pk_bf16_f32 %0, %1, %2" : "=v"(pk[j]) : "v"(r0), "v"(r1));
            }
            *(int4*)(s_lds + px_l * 296 + kk * 32 + q * 8) = make_int4(pk[0], pk[1], pk[2], pk[3]);
        }
        __syncthreads();            // A complete; feat window consumed
        if (c < 7) STAGE(ci0 + 32); // restage window (latency hidden by MFMA)

        // ---- MFMA over 9 taps ----
#pragma unroll
        for (int kk = 0; kk < 9; kk++) {
            short8 af[2];
#pragma unroll
            for (int mf = 0; mf < 2; mf++)
                af[mf] = *(const short8*)(s_lds + (mf * 16 + l15) * 296 + kk * 32 + lq * 8);
#pragma unroll
            for (int nf = 0; nf < 4; nf++) {
                int co = wc * 64 + nf * 16 + l15;
                short8 bf = *(const short8*)(wtb + ((size_t)(kk * C_ + co)) * C_ + ci0 + lq * 8);
#pragma unroll
                for (int mf = 0; mf < 2; mf++)
                    acc[mf][nf] = __builtin_amdgcn_mfma_f32_16x16x32_bf16(
                        af[mf], bf, acc[mf][nf], 0, 0, 0);
            }
        }
        __syncthreads();            // stage drained (vmcnt0); A free
    }

    // ---- epilogue: relu -> bf16 NHWC ----
#pragma unroll
    for (int nf = 0; nf < 4; nf++) {
        int co = wc * 64 + nf * 16 + l15;
#pragma unroll
        for (int mf = 0; mf < 2; mf++) {
#pragma unroll
            for (int r = 0; r < 4; r++) {
                int px_l = mf * 16 + lq * 4 + r;
                int y = y0 + (px_l >> 3), x = x0 + (px_l & 7);
                out[((size_t)(b * HW_ + y * W_ + x)) * C_ + co] =
                    f2b(fmaxf(acc[mf][nf][r], 0.f));
            }
        }
    }
}

// ---------------- 1x1 conv body from NHWC bf16 feat, out NCHW fp32 ----------------
template <int NOg>
__device__ __forceinline__ void conv1x1_body(
    const unsigned short* __restrict__ feat, const float* __restrict__ w,
    const float* __restrict__ bias, const float* __restrict__ addsrc,
    float* __restrict__ outp, int O)
{
    const int lane = threadIdx.x & 63, og = threadIdx.x >> 6;
    const int px = blockIdx.x * 64 + lane;
    const int b = (px >= HW_) ? 1 : 0;
    const int rem = px - b * HW_;
    const short8* f8 = (const short8*)(feat + (size_t)px * C_);

    float acc[NOg];
#pragma unroll
    for (int j = 0; j < NOg; j++) acc[j] = 0.f;

    for (int c8 = 0; c8 < 32; c8++) {
        short8 v8 = f8[c8];
        float vf[8];
#pragma unroll
        for (int e = 0; e < 8; e++) vf[e] = b2f((unsigned short)v8[e]);
#pragma unroll
        for (int j = 0; j < NOg; j++) {
            int o = og * NOg + j;
            if (o < O) {
                const float* wr = w + (size_t)o * C_ + c8 * 8;
                float4 w0 = *(const float4*)wr;
                float4 w1 = *(const float4*)(wr + 4);
                acc[j] = fmaf(vf[0], w0.x, acc[j]);
                acc[j] = fmaf(vf[1], w0.y, acc[j]);
                acc[j] = fmaf(vf[2], w0.z, acc[j]);
                acc[j] = fmaf(vf[3], w0.w, acc[j]);
                acc[j] = fmaf(vf[4], w1.x, acc[j]);
                acc[j] = fmaf(vf[5], w1.y, acc[j]);
                acc[j] = fmaf(vf[6], w1.z, acc[j]);
                acc[j] = fmaf(vf[7], w1.w, acc[j]);
            }
        }
    }
#pragma unroll
    for (int j = 0; j < NOg; j++) {
        int o = og * NOg + j;
        if (o < O) {
            float val = acc[j] + bias[o];
            size_t oi = ((size_t)(b * O + o)) * HW_ + rem;
            if (addsrc) val += addsrc[oi];
            outp[oi] = val;
        }
    }
}

template <int NOg>
__global__ __launch_bounds__(256) void conv1x1_kernel(
    const unsigned short* __restrict__ feat, const float* __restrict__ w,
    const float* __restrict__ bias, const float* __restrict__ addsrc,
    float* __restrict__ outp, int O)
{
    conv1x1_body<NOg>(feat, w, bias, addsrc, outp, O);
}

// Dual tail: y==0 -> cls head (O=80), y==1 -> refine head (O=18 + addsrc).
__global__ __launch_bounds__(256) void conv1x1_dual_kernel(
    const unsigned short* __restrict__ fA, const float* __restrict__ wA,
    const float* __restrict__ bA_, float* __restrict__ outA,
    const unsigned short* __restrict__ fB, const float* __restrict__ wB,
    const float* __restrict__ bB_, const float* __restrict__ addB,
    float* __restrict__ outB)
{
    if (blockIdx.y == 0) conv1x1_body<20>(fA, wA, bA_, nullptr, outA, 80);
    else                 conv1x1_body<5>(fB, wB, bB_, addB, outB, 18);
}

// ---------------- host launch ----------------
extern "C" void kernel_launch(void* const* d_in, const int* in_sizes, int n_in,
                              void* d_out, int out_size, void* d_ws, size_t ws_size,
                              hipStream_t stream)
{
    (void)in_sizes; (void)n_in; (void)out_size; (void)ws_size;

    const float* x           = (const float*)d_in[0];
    const float* cls_w       = (const float*)d_in[1];
    const float* cls_b       = (const float*)d_in[2];
    const float* cls_gn_g    = (const float*)d_in[3];
    const float* cls_gn_b    = (const float*)d_in[4];
    const float* reg_w       = (const float*)d_in[5];
    const float* reg_b       = (const float*)d_in[6];
    const float* reg_gn_g    = (const float*)d_in[7];
    const float* reg_gn_b    = (const float*)d_in[8];
    const float* init_conv_w = (const float*)d_in[9];
    const float* init_conv_b = (const float*)d_in[10];
    const float* init_out_w  = (const float*)d_in[11];
    const float* init_out_b  = (const float*)d_in[12];
    const float* cls_dcn_w   = (const float*)d_in[13];
    const float* cls_out_w   = (const float*)d_in[14];
    const float* cls_out_b   = (const float*)d_in[15];
    const float* ref_dcn_w   = (const float*)d_in[16];
    const float* ref_out_w   = (const float*)d_in[17];
    const float* ref_out_b   = (const float*)d_in[18];

    float* out = (float*)d_out;

    const size_t NF = (size_t)B_ * C_ * HW_;   // 7,782,400 elements
    unsigned short* xb16   = (unsigned short*)d_ws;
    unsigned short* bA     = xb16 + NF;
    unsigned short* bB     = bA + NF;
    unsigned short* bC     = bB + NF;
    unsigned short* bD     = bC + NF;
    unsigned short* wtbAll = bD + NF;                    // 9 x 589,824 bf16
    float* statsAll = (float*)(wtbAll + 9 * WSLOT);      // 3x256 stats + 32 zbuf
    const unsigned short* zbuf = (const unsigned short*)(statsAll + 768);

    const dim3 convGrid2(10, 25, 4);      // dual tower; x = xt*2+ch
    const dim3 convGrid1(10, 25, 2);      // single tower (tw=0)
    const dim3 wprepGridAll(C_, 9, 9);
    const dim3 nhwcGrid((HW_ + 63) / 64, C_ / 64, B_);
    const dim3 gnGrid((B_ * HW_ * 32) / 256, 2);
    const dim3 deformGrid(W_ / 8, H_ / 4, 4);        // (19, 25, 4) merged towers
    const int  px_blocks = (B_ * HW_) / 64;          // 475
    const dim3 tailGrid(px_blocks, 2);

    // --- all weight preps + stats zeroing, one dispatch up front ---
    wprep_all_kernel<<<wprepGridAll, 256, 0, stream>>>(
        cls_w, reg_w, init_conv_w, cls_dcn_w, ref_dcn_w, wtbAll, statsAll);
    to_nhwc_b16_kernel<<<nhwcGrid, 256, 0, stream>>>(x, xb16);

    // --- stage 0: xb16 -> bA (cls), bC (pts) ---
    conv3x3_mfma12_kernel<<<convGrid2, 256, 0, stream>>>(
        xb16, xb16, wtbAll, wtbAll + 3 * WSLOT, cls_b, reg_b, bA, bC,
        statsAll, zbuf, 0);
    gn2_apply_kernel<<<gnGrid, 256, 0, stream>>>(
        bA, bC, statsAll, cls_gn_g, cls_gn_b, reg_gn_g, reg_gn_b);

    // --- stage 1: bA -> bB, bC -> bD ---
    conv3x3_mfma12_kernel<<<convGrid2, 256, 0, stream>>>(
        bA, bC, wtbAll + 1 * WSLOT, wtbAll + 4 * WSLOT, cls_b + C_, reg_b + C_,
        bB, bD, statsAll + 256, zbuf, 0);
    gn2_apply_kernel<<<gnGrid, 256, 0, stream>>>(
        bB, bD, statsAll + 256, cls_gn_g + C_, cls_gn_b + C_,
        reg_gn_g + C_, reg_gn_b + C_);

    // --- stage 2: bB -> bA (clsF), bD -> bC (ptsF) ---
    conv3x3_mfma12_kernel<<<convGrid2, 256, 0, stream>>>(
        bB, bD, wtbAll + 2 * WSLOT, wtbAll + 5 * WSLOT, cls_b + 2 * C_,
        reg_b + 2 * C_, bA, bC, statsAll + 512, zbuf, 0);
    gn2_apply_kernel<<<gnGrid, 256, 0, stream>>>(
        bA, bC, statsAll + 512, cls_gn_g + 2 * C_, cls_gn_b + 2 * C_,
        reg_gn_g + 2 * C_, reg_gn_b + 2 * C_);

    // --- init branch: relu(conv3x3(ptsF=bC)) -> bD -> 1x1 -> pts_out_init ---
    conv3x3_mfma12_kernel<<<convGrid1, 256, 0, stream>>>(
        bC, nullptr, wtbAll + 6 * WSLOT, nullptr, init_conv_b, nullptr,
        bD, nullptr, nullptr, zbuf, 1);
    conv1x1_kernel<5><<<px_blocks, 256, 0, stream>>>(
        bD, init_out_w, init_out_b, nullptr, out + OFF_INIT, 18);

    // --- deforms merged into one dispatch (z=4: b, tower) ---
    deform3_mfma_kernel<<<deformGrid, 256, 0, stream>>>(
        bA, bC, out + OFF_INIT, wtbAll + 7 * WSLOT, wtbAll + 8 * WSLOT,
        bB, bD, zbuf);

    // --- tails merged into one dispatch ---
    conv1x1_dual_kernel<<<tailGrid, 256, 0, stream>>>(
        bB, cls_out_w, cls_out_b, out,
        bD, ref_out_w, ref_out_b, out + OFF_INIT, out + OFF_REF);
}